// Round 5
// baseline (327.945 us; speedup 1.0000x reference)
//
#include <hip/hip_runtime.h>
#include <hip/hip_fp16.h>

// Problem constants
#define B_   128
#define N_   68
#define C_   3
#define P_   32
#define K_   16
#define FD_  64
#define GH_  128
#define EG_  544          // 8*N
#define T_   8704         // B*N
#define HT_  4352         // T/2
#define FLAT_ 4096        // K*16*16
#define FCH_ 16           // f-chunks in lin1 (K-split of 256)

typedef __attribute__((ext_vector_type(8))) _Float16 half8;
typedef __attribute__((ext_vector_type(2))) _Float16 half2v;
typedef __attribute__((ext_vector_type(4))) float   floatx4;
typedef __attribute__((ext_vector_type(4))) unsigned int uint32x4;

// LDS image pitches chosen for bank-conflict-free MFMA B-fragment reads:
// row pitch 40 halves (20 dwords), channel pitch 1400 halves (700 dwords).
#define ROWP 40
#define CHP  1400

// ---------------------------------------------------------------------------
// K0: weight-fragment prep (once per node type, not per block).
// wfrag layout: [n][sx][type][k][slot32] halves; type 0 = main, 1 = corr.
// ---------------------------------------------------------------------------
__global__ __launch_bounds__(256) void wfrag_prep_kernel(
    const float* __restrict__ conv_w, _Float16* __restrict__ wfrag) {
  const int n = blockIdx.x;
  const int tid = threadIdx.x;
  const float* wp = conv_w + (size_t)n * (K_ * 27);
  _Float16* out = wfrag + (size_t)n * 2048;
  for (int i = tid; i < 2048; i += 256) {
    int sx   = (i >> 10) & 1;
    int type = (i >> 9) & 1;
    int k    = (i >> 5) & 15;
    int slot = i & 31;
    float v = 0.0f;
    if (type == 0) {
      int q = slot >> 3, r = (slot >> 2) & 1, col = slot & 3;
      int cr = q * 2 + r, c = cr / 3, dy = cr - c * 3, dx = col - sx;
      if (dx >= 0 && dx < 3) v = wp[k * 27 + c * 9 + dy * 3 + dx];
    } else {
      int q = slot >> 3, j = slot & 7;
      if (q == 0 && j < 4) {
        int dx = j - sx;
        if (dx >= 0 && dx < 3) v = wp[k * 27 + 24 + dx];  // c2,dy2 row
      }
    }
    out[i] = (_Float16)v;
  }
}

// ---------------------------------------------------------------------------
// K1: conv3x3(SAME)+bias+relu+maxpool2x2 -> pooled[T][4096] fp16.
// TWO images per block (t and t+HT_, same node type n): fragments loaded once,
// one staging barrier for both, doubled independent MFMA work per wave.
// ---------------------------------------------------------------------------
__global__ __launch_bounds__(256) void conv_pool_kernel(
    const float* __restrict__ x, const _Float16* __restrict__ wfrag,
    const float* __restrict__ conv_b, _Float16* __restrict__ pooled) {
  const int t0 = blockIdx.x;            // [0, HT_)
  const int n = t0 % N_;
  const int tid = threadIdx.x;

  __shared__ _Float16 xsh[2][3 * CHP];  // two images

  const int lane = tid & 63;
  const int lr = lane & 15, q = lane >> 4;
  const int wave = tid >> 6;
  const int ldy = lr >> 3, ldx = lr & 7;

  // ---- issue x loads for both images ----
  float4 xv[2][3];
  #pragma unroll
  for (int im = 0; im < 2; im++) {
    const float4* xg = (const float4*)(x + (size_t)(t0 + im * HT_) * (C_ * P_ * P_));
    #pragma unroll
    for (int j = 0; j < 3; j++) xv[im][j] = xg[tid + j * 256];
  }

  // ---- fragment loads (L2-resident wfrag; shared by both images) ----
  const _Float16* wf = wfrag + (size_t)n * 2048 + lr * 32 + q * 8;
  half8 aMain0 = *(const half8*)&wf[0 * 512];   // sx0 main
  half8 aCorr0 = *(const half8*)&wf[1 * 512];   // sx0 corr
  half8 aMain1 = *(const half8*)&wf[2 * 512];   // sx1 main
  half8 aCorr1 = *(const half8*)&wf[3 * 512];   // sx1 corr
  floatx4 cbias = *(const floatx4*)&conv_b[(size_t)n * K_ + q * 4];

  // ---- zero the 1-wide border (both images) ----
  #pragma unroll
  for (int im = 0; im < 2; im++) {
    for (int i = tid; i < 396; i += 256) {
      int c = i / 132, j = i - c * 132;
      int off;
      if (j < 34)       off = j;
      else if (j < 68)  off = 33 * ROWP + (j - 34);
      else if (j < 100) off = (j - 68 + 1) * ROWP;
      else              off = (j - 100 + 1) * ROWP + 33;
      xsh[im][c * CHP + off] = (_Float16)0.0f;
    }
  }
  // ---- interior staging ----
  #pragma unroll
  for (int im = 0; im < 2; im++) {
    #pragma unroll
    for (int j = 0; j < 3; j++) {
      int f0 = (tid + j * 256) * 4;
      int c = f0 >> 10, rem = f0 & 1023, y = rem >> 5, xc = rem & 31;
      _Float16* dp = &xsh[im][c * CHP + (y + 1) * ROWP + xc + 1];
      dp[0] = (_Float16)xv[im][j].x; dp[1] = (_Float16)xv[im][j].y;
      dp[2] = (_Float16)xv[im][j].z; dp[3] = (_Float16)xv[im][j].w;
    }
  }
  __syncthreads();

  // per-lane chunk-row offsets (chunk-rows cr = 2q, 2q+1)
  const int crL = q * 2, crH = crL + 1;
  const int cL = crL / 3, dyL = crL - cL * 3;
  const int cH = crH / 3, dyH = crH - cH * 3;
  const int offL = cL * CHP + dyL * ROWP;
  const int offH = cH * CHP + dyH * ROWP;
  const int offC = 2 * CHP + 2 * ROWP;

  #pragma unroll
  for (int im = 0; im < 2; im++) {
    const _Float16* chL = &xsh[im][offL];
    const _Float16* chH = &xsh[im][offH];
    const _Float16* chC = &xsh[im][offC];
    const size_t tcur = (size_t)(t0 + im * HT_);

    #pragma unroll
    for (int i = 0; i < 4; i++) {
      const int qq = wave * 4 + i;
      const int py0 = (qq >> 1) * 2, px0 = (qq & 1) * 8;
      const int py = py0 + ldy, px = px0 + ldx;
      const int ebase = py * (2 * ROWP) + px * 2;
      const _Float16* pL = chL + ebase;
      const _Float16* pH = chH + ebase;
      const _Float16* pC = chC + ebase;

      floatx4 mx;
      #pragma unroll
      for (int sy = 0; sy < 2; sy++) {
        unsigned int uL0 = *(const unsigned int*)&pL[sy * ROWP];
        unsigned int uL1 = *(const unsigned int*)&pL[sy * ROWP + 2];
        unsigned int uH0 = *(const unsigned int*)&pH[sy * ROWP];
        unsigned int uH1 = *(const unsigned int*)&pH[sy * ROWP + 2];
        unsigned int uC0 = *(const unsigned int*)&pC[sy * ROWP];
        unsigned int uC1 = *(const unsigned int*)&pC[sy * ROWP + 2];
        half8 bMain = __builtin_bit_cast(half8, (uint32x4){uL0, uL1, uH0, uH1});
        half8 bCorr = __builtin_bit_cast(half8, (uint32x4){uC0, uC1, uC0, uC1});
        floatx4 d0 = __builtin_amdgcn_mfma_f32_16x16x32_f16(aCorr0, bCorr, cbias, 0, 0, 0);
        d0 = __builtin_amdgcn_mfma_f32_16x16x32_f16(aMain0, bMain, d0, 0, 0, 0);
        floatx4 d1 = __builtin_amdgcn_mfma_f32_16x16x32_f16(aCorr1, bCorr, cbias, 0, 0, 0);
        d1 = __builtin_amdgcn_mfma_f32_16x16x32_f16(aMain1, bMain, d1, 0, 0, 0);
        floatx4 m;
        m[0] = fmaxf(d0[0], d1[0]); m[1] = fmaxf(d0[1], d1[1]);
        m[2] = fmaxf(d0[2], d1[2]); m[3] = fmaxf(d0[3], d1[3]);
        if (sy == 0) mx = m;
        else {
          mx[0] = fmaxf(mx[0], m[0]); mx[1] = fmaxf(mx[1], m[1]);
          mx[2] = fmaxf(mx[2], m[2]); mx[3] = fmaxf(mx[3], m[3]);
        }
      }
      _Float16* op = pooled + tcur * FLAT_ + q * 1024 + py * 16 + px;
      op[0]   = (_Float16)fmaxf(mx[0], 0.0f);
      op[256] = (_Float16)fmaxf(mx[1], 0.0f);
      op[512] = (_Float16)fmaxf(mx[2], 0.0f);
      op[768] = (_Float16)fmaxf(mx[3], 0.0f);
    }
  }
}

// ---------------------------------------------------------------------------
// K2: per-type linear via fp16 MFMA 16x16x32. Grid = 68 types x 16 f-chunks.
// Writes DETERMINISTIC partials, layout part[t][fc][64] fp32 (contiguous per
// node for the fused tail kernel).
// ---------------------------------------------------------------------------
__global__ __launch_bounds__(256) void lin1_mfma_kernel(
    const _Float16* __restrict__ pooled, const float* __restrict__ lin1_w,
    float* __restrict__ part) {
  const int n   = blockIdx.x >> 4;
  const int fc  = blockIdx.x & 15;
  const int tid = threadIdx.x;
  const int wave = tid >> 6, lane = tid & 63;
  const int q = lane >> 4, lr = lane & 15;

  __shared__ __align__(16) _Float16 As[128 * 72];  // 128 rows x 64 k, pitch 72
  __shared__ __align__(16) _Float16 Bt[64 * 72];   // 64 outs x 64 k

  floatx4 acc[2][4];
  #pragma unroll
  for (int mt = 0; mt < 2; mt++)
    #pragma unroll
    for (int nt = 0; nt < 4; nt++)
      acc[mt][nt] = (floatx4){0.f, 0.f, 0.f, 0.f};

  const int f_base = fc * 256;
  for (int step = 0; step < 4; step++) {
    const int f0 = f_base + step * 64;

    // stage A: 128 rows x 64 fp16; 1024 16B-chunks, 4/thread
    #pragma unroll
    for (int j = 0; j < 4; j++) {
      int idx = tid + j * 256;
      int r = idx >> 3, ch = idx & 7;
      uint4 v = *(const uint4*)&pooled[(size_t)(r * N_ + n) * FLAT_ + f0 + ch * 8];
      *(uint4*)&As[r * 72 + ch * 8] = v;
    }
    // stage B: w slice [64 k][64 o]; cvt fp32->fp16 + transpose via half2 packs
    const float* wg = &lin1_w[(size_t)n * (FLAT_ * FD_) + (size_t)f0 * FD_];
    #pragma unroll
    for (int it = 0; it < 2; it++) {
      int p = tid + it * 256;            // 512 (k-pair, o-quad) units
      int o0 = (p & 15) * 4, k0 = (p >> 4) * 2;
      const float* wgk = wg + k0 * 64 + o0;
      float4 va = *(const float4*)wgk;
      float4 vb = *(const float4*)(wgk + 64);
      *(half2v*)&Bt[(o0 + 0) * 72 + k0] = (half2v){(_Float16)va.x, (_Float16)vb.x};
      *(half2v*)&Bt[(o0 + 1) * 72 + k0] = (half2v){(_Float16)va.y, (_Float16)vb.y};
      *(half2v*)&Bt[(o0 + 2) * 72 + k0] = (half2v){(_Float16)va.z, (_Float16)vb.z};
      *(half2v*)&Bt[(o0 + 3) * 72 + k0] = (half2v){(_Float16)va.w, (_Float16)vb.w};
    }
    __syncthreads();

    #pragma unroll
    for (int kh = 0; kh < 2; kh++) {
      half8 af[2], bf[4];
      #pragma unroll
      for (int mt = 0; mt < 2; mt++)
        af[mt] = *(const half8*)&As[(wave * 32 + mt * 16 + lr) * 72 + kh * 32 + q * 8];
      #pragma unroll
      for (int nt = 0; nt < 4; nt++)
        bf[nt] = *(const half8*)&Bt[(nt * 16 + lr) * 72 + kh * 32 + q * 8];
      #pragma unroll
      for (int mt = 0; mt < 2; mt++)
        #pragma unroll
        for (int nt = 0; nt < 4; nt++)
          acc[mt][nt] = __builtin_amdgcn_mfma_f32_16x16x32_f16(
              af[mt], bf[nt], acc[mt][nt], 0, 0, 0);
    }
    __syncthreads();
  }

  // store partials: part[t][fc][64]; D layout col=lane&15, row=quad*4+reg
  #pragma unroll
  for (int mt = 0; mt < 2; mt++) {
    #pragma unroll
    for (int v = 0; v < 4; v++) {
      int r = wave * 32 + mt * 16 + q * 4 + v;
      size_t base = ((size_t)(r * N_ + n) * FCH_ + fc) * FD_;
      #pragma unroll
      for (int nt = 0; nt < 4; nt++)
        part[base + nt * 16 + lr] = acc[mt][nt][v];
    }
  }
}

// ---------------------------------------------------------------------------
// K3: fused tail, one block per graph (128 blocks x 512 threads).
//   feats = relu(sum16 part + lin1_b)  -> LDS fS[68][64]
//   GCN agg with LDS atomics           -> aS[68][64]
//   per-graph GEMM + mean-pool + MLP   -> out[b][2]
// Bank notes: scatter has all 64 lanes on distinct f of one edge -> 2-way
// (free); head GEMM reads aS at wave-uniform address (broadcast, free).
// ---------------------------------------------------------------------------
__global__ __launch_bounds__(512) void gcn_tail_kernel(
    const float* __restrict__ part, const float* __restrict__ lin1_b,
    const int* __restrict__ edge_index, const float* __restrict__ gcn_w,
    const float* __restrict__ gcn_b, const float* __restrict__ w1,
    const float* __restrict__ b1, const float* __restrict__ w2,
    const float* __restrict__ b2, float* __restrict__ out) {
  const int b = blockIdx.x;
  const int tid = threadIdx.x;

  __shared__ float fS[N_ * 64], aS[N_ * 64];
  __shared__ int   esrcS[EG_], edstS[EG_];
  __shared__ float nrmS[EG_];
  __shared__ int   degS[N_];
  __shared__ float disS[N_];
  __shared__ float wS[FD_ * GH_];    // 32 KB
  __shared__ float gP[4][GH_];
  __shared__ float z1S[64];

  if (tid < N_) degS[tid] = 0;
  // edges
  const int* srcp = edge_index;
  const int* dstp = edge_index + (B_ * EG_);
  const int e0 = b * EG_, nbase = b * N_;
  for (int e = tid; e < EG_; e += 512) {
    esrcS[e] = srcp[e0 + e] - nbase;
    edstS[e] = dstp[e0 + e] - nbase;
  }
  // stage gcn_w
  #pragma unroll
  for (int j = 0; j < 4; j++)
    ((float4*)wS)[tid + j * 512] = ((const float4*)gcn_w)[tid + j * 512];
  // feats: sum 16 partials + bias, relu (part rows contiguous per node)
  for (int idx = tid; idx < N_ * 64; idx += 512) {
    int i = idx >> 6, f = idx & 63;
    const float* pp = &part[(size_t)((b * N_ + i) * FCH_) * FD_ + f];
    float s = lin1_b[i * FD_ + f];
    #pragma unroll
    for (int fc = 0; fc < FCH_; fc++) s += pp[fc * FD_];
    fS[idx] = fmaxf(s, 0.f);
  }
  __syncthreads();
  for (int e = tid; e < EG_; e += 512) atomicAdd(&degS[edstS[e]], 1);
  __syncthreads();
  if (tid < N_) disS[tid] = rsqrtf((float)(degS[tid] + 1));   // +1 self-loop
  __syncthreads();
  for (int e = tid; e < EG_; e += 512)
    nrmS[e] = disS[esrcS[e]] * disS[edstS[e]];
  for (int idx = tid; idx < N_ * 64; idx += 512) {
    int i = idx >> 6;
    float d = disS[i];
    aS[idx] = d * d * fS[idx];
  }
  __syncthreads();
  for (int idx = tid; idx < EG_ * 64; idx += 512) {
    int e = idx >> 6, f = idx & 63;
    atomicAdd(&aS[edstS[e] * 64 + f], nrmS[e] * fS[esrcS[e] * 64 + f]);
  }
  __syncthreads();

  // head GEMM [68,64]@[64,128] + relu + mean-pool
  const int j = tid & 127, ig = tid >> 7;
  float wc[64];
  #pragma unroll
  for (int k = 0; k < 64; k++) wc[k] = wS[k * GH_ + j];
  const float bias = gcn_b[j];
  float gsum = 0.f;
  for (int i = ig; i < N_; i += 4) {
    float acc = bias;
    #pragma unroll
    for (int kq = 0; kq < 16; kq++) {
      float4 a = *(const float4*)&aS[i * 64 + kq * 4];   // broadcast
      acc += a.x * wc[kq * 4] + a.y * wc[kq * 4 + 1]
           + a.z * wc[kq * 4 + 2] + a.w * wc[kq * 4 + 3];
    }
    gsum += fmaxf(acc, 0.f);
  }
  gP[ig][j] = gsum;
  __syncthreads();
  if (tid < GH_)
    gP[0][tid] = (gP[0][tid] + gP[1][tid] + gP[2][tid] + gP[3][tid]) * (1.f / 68.f);
  __syncthreads();
  if (tid < 64) {
    float s = b1[tid];
    #pragma unroll 8
    for (int jj = 0; jj < GH_; jj++) s += gP[0][jj] * w1[jj * 64 + tid];
    z1S[tid] = fmaxf(s, 0.f);
  }
  __syncthreads();
  if (tid < 2) {
    float s = b2[tid];
    #pragma unroll 8
    for (int jj = 0; jj < 64; jj++) s += z1S[jj] * w2[jj * 2 + tid];
    out[b * 2 + tid] = s;
  }
}

// ---------------------------------------------------------------------------
extern "C" void kernel_launch(void* const* d_in, const int* in_sizes, int n_in,
                              void* d_out, int out_size, void* d_ws, size_t ws_size,
                              hipStream_t stream) {
  const float* x        = (const float*)d_in[0];
  const int*   edge_idx = (const int*)d_in[1];
  // d_in[2] = batch (layout known: t -> t/N), unused
  const float* conv_w   = (const float*)d_in[3];
  const float* conv_b   = (const float*)d_in[4];
  const float* lin1_w   = (const float*)d_in[5];
  const float* lin1_b   = (const float*)d_in[6];
  const float* gcn_w    = (const float*)d_in[7];
  const float* gcn_b    = (const float*)d_in[8];
  const float* mlp_w1   = (const float*)d_in[9];
  const float* mlp_b1   = (const float*)d_in[10];
  const float* mlp_w2   = (const float*)d_in[11];
  const float* mlp_b2   = (const float*)d_in[12];
  float* outp = (float*)d_out;

  char* wsb = (char*)d_ws;
  _Float16* pooled = (_Float16*)wsb;                               // 71.3 MB
  float* part  = (float*)(wsb + (size_t)T_ * FLAT_ * 2);           // 35.7 MB
  _Float16* wfrag = (_Float16*)(part + (size_t)T_ * FCH_ * FD_);   //  0.27 MB

  wfrag_prep_kernel<<<N_, 256, 0, stream>>>(conv_w, wfrag);
  conv_pool_kernel<<<HT_, 256, 0, stream>>>(x, wfrag, conv_b, pooled);
  lin1_mfma_kernel<<<N_ * FCH_, 256, 0, stream>>>(pooled, lin1_w, part);
  gcn_tail_kernel<<<B_, 512, 0, stream>>>(part, lin1_b, edge_idx, gcn_w, gcn_b,
                                          mlp_w1, mlp_b1, mlp_w2, mlp_b2, outp);
}

// Round 6
// 317.298 us; speedup vs baseline: 1.0336x; 1.0336x over previous
//
#include <hip/hip_runtime.h>
#include <hip/hip_fp16.h>

// Problem constants
#define B_   128
#define N_   68
#define C_   3
#define P_   32
#define K_   16
#define FD_  64
#define GH_  128
#define EG_  544          // 8*N
#define T_   8704         // B*N
#define HT_  4352         // T/2
#define FLAT_ 4096        // K*16*16
#define FCH_ 16           // f-chunks in lin1 (K-split of 256)

typedef __attribute__((ext_vector_type(8))) _Float16 half8;
typedef __attribute__((ext_vector_type(2))) _Float16 half2v;
typedef __attribute__((ext_vector_type(4))) float   floatx4;
typedef __attribute__((ext_vector_type(4))) unsigned int uint32x4;

// LDS image pitches chosen for bank-conflict-free MFMA B-fragment reads:
// row pitch 40 halves (20 dwords), channel pitch 1400 halves (700 dwords).
#define ROWP 40
#define CHP  1400

// ---------------------------------------------------------------------------
// K0: weight-fragment prep (once per node type, not per block).
// wfrag layout: [n][sx][type][k][slot32] halves; type 0 = main, 1 = corr.
// ---------------------------------------------------------------------------
__global__ __launch_bounds__(256) void wfrag_prep_kernel(
    const float* __restrict__ conv_w, _Float16* __restrict__ wfrag) {
  const int n = blockIdx.x;
  const int tid = threadIdx.x;
  const float* wp = conv_w + (size_t)n * (K_ * 27);
  _Float16* out = wfrag + (size_t)n * 2048;
  for (int i = tid; i < 2048; i += 256) {
    int sx   = (i >> 10) & 1;
    int type = (i >> 9) & 1;
    int k    = (i >> 5) & 15;
    int slot = i & 31;
    float v = 0.0f;
    if (type == 0) {
      int q = slot >> 3, r = (slot >> 2) & 1, col = slot & 3;
      int cr = q * 2 + r, c = cr / 3, dy = cr - c * 3, dx = col - sx;
      if (dx >= 0 && dx < 3) v = wp[k * 27 + c * 9 + dy * 3 + dx];
    } else {
      int q = slot >> 3, j = slot & 7;
      if (q == 0 && j < 4) {
        int dx = j - sx;
        if (dx >= 0 && dx < 3) v = wp[k * 27 + 24 + dx];  // c2,dy2 row
      }
    }
    out[i] = (_Float16)v;
  }
}

// ---------------------------------------------------------------------------
// K1: conv3x3(SAME)+bias+relu+maxpool2x2 -> pooled[T][4096] fp16.
// TWO images per block (t and t+HT_, same node type n): fragments loaded once,
// one staging barrier for both, doubled independent MFMA work per wave.
// ---------------------------------------------------------------------------
__global__ __launch_bounds__(256) void conv_pool_kernel(
    const float* __restrict__ x, const _Float16* __restrict__ wfrag,
    const float* __restrict__ conv_b, _Float16* __restrict__ pooled) {
  const int t0 = blockIdx.x;            // [0, HT_)
  const int n = t0 % N_;
  const int tid = threadIdx.x;

  __shared__ _Float16 xsh[2][3 * CHP];  // two images

  const int lane = tid & 63;
  const int lr = lane & 15, q = lane >> 4;
  const int wave = tid >> 6;
  const int ldy = lr >> 3, ldx = lr & 7;

  // ---- issue x loads for both images ----
  float4 xv[2][3];
  #pragma unroll
  for (int im = 0; im < 2; im++) {
    const float4* xg = (const float4*)(x + (size_t)(t0 + im * HT_) * (C_ * P_ * P_));
    #pragma unroll
    for (int j = 0; j < 3; j++) xv[im][j] = xg[tid + j * 256];
  }

  // ---- fragment loads (L2-resident wfrag; shared by both images) ----
  const _Float16* wf = wfrag + (size_t)n * 2048 + lr * 32 + q * 8;
  half8 aMain0 = *(const half8*)&wf[0 * 512];   // sx0 main
  half8 aCorr0 = *(const half8*)&wf[1 * 512];   // sx0 corr
  half8 aMain1 = *(const half8*)&wf[2 * 512];   // sx1 main
  half8 aCorr1 = *(const half8*)&wf[3 * 512];   // sx1 corr
  floatx4 cbias = *(const floatx4*)&conv_b[(size_t)n * K_ + q * 4];

  // ---- zero the 1-wide border (both images) ----
  #pragma unroll
  for (int im = 0; im < 2; im++) {
    for (int i = tid; i < 396; i += 256) {
      int c = i / 132, j = i - c * 132;
      int off;
      if (j < 34)       off = j;
      else if (j < 68)  off = 33 * ROWP + (j - 34);
      else if (j < 100) off = (j - 68 + 1) * ROWP;
      else              off = (j - 100 + 1) * ROWP + 33;
      xsh[im][c * CHP + off] = (_Float16)0.0f;
    }
  }
  // ---- interior staging ----
  #pragma unroll
  for (int im = 0; im < 2; im++) {
    #pragma unroll
    for (int j = 0; j < 3; j++) {
      int f0 = (tid + j * 256) * 4;
      int c = f0 >> 10, rem = f0 & 1023, y = rem >> 5, xc = rem & 31;
      _Float16* dp = &xsh[im][c * CHP + (y + 1) * ROWP + xc + 1];
      dp[0] = (_Float16)xv[im][j].x; dp[1] = (_Float16)xv[im][j].y;
      dp[2] = (_Float16)xv[im][j].z; dp[3] = (_Float16)xv[im][j].w;
    }
  }
  __syncthreads();

  // per-lane chunk-row offsets (chunk-rows cr = 2q, 2q+1)
  const int crL = q * 2, crH = crL + 1;
  const int cL = crL / 3, dyL = crL - cL * 3;
  const int cH = crH / 3, dyH = crH - cH * 3;
  const int offL = cL * CHP + dyL * ROWP;
  const int offH = cH * CHP + dyH * ROWP;
  const int offC = 2 * CHP + 2 * ROWP;

  #pragma unroll
  for (int im = 0; im < 2; im++) {
    const _Float16* chL = &xsh[im][offL];
    const _Float16* chH = &xsh[im][offH];
    const _Float16* chC = &xsh[im][offC];
    const size_t tcur = (size_t)(t0 + im * HT_);

    #pragma unroll
    for (int i = 0; i < 4; i++) {
      const int qq = wave * 4 + i;
      const int py0 = (qq >> 1) * 2, px0 = (qq & 1) * 8;
      const int py = py0 + ldy, px = px0 + ldx;
      const int ebase = py * (2 * ROWP) + px * 2;
      const _Float16* pL = chL + ebase;
      const _Float16* pH = chH + ebase;
      const _Float16* pC = chC + ebase;

      floatx4 mx;
      #pragma unroll
      for (int sy = 0; sy < 2; sy++) {
        unsigned int uL0 = *(const unsigned int*)&pL[sy * ROWP];
        unsigned int uL1 = *(const unsigned int*)&pL[sy * ROWP + 2];
        unsigned int uH0 = *(const unsigned int*)&pH[sy * ROWP];
        unsigned int uH1 = *(const unsigned int*)&pH[sy * ROWP + 2];
        unsigned int uC0 = *(const unsigned int*)&pC[sy * ROWP];
        unsigned int uC1 = *(const unsigned int*)&pC[sy * ROWP + 2];
        half8 bMain = __builtin_bit_cast(half8, (uint32x4){uL0, uL1, uH0, uH1});
        half8 bCorr = __builtin_bit_cast(half8, (uint32x4){uC0, uC1, uC0, uC1});
        floatx4 d0 = __builtin_amdgcn_mfma_f32_16x16x32_f16(aCorr0, bCorr, cbias, 0, 0, 0);
        d0 = __builtin_amdgcn_mfma_f32_16x16x32_f16(aMain0, bMain, d0, 0, 0, 0);
        floatx4 d1 = __builtin_amdgcn_mfma_f32_16x16x32_f16(aCorr1, bCorr, cbias, 0, 0, 0);
        d1 = __builtin_amdgcn_mfma_f32_16x16x32_f16(aMain1, bMain, d1, 0, 0, 0);
        floatx4 m;
        m[0] = fmaxf(d0[0], d1[0]); m[1] = fmaxf(d0[1], d1[1]);
        m[2] = fmaxf(d0[2], d1[2]); m[3] = fmaxf(d0[3], d1[3]);
        if (sy == 0) mx = m;
        else {
          mx[0] = fmaxf(mx[0], m[0]); mx[1] = fmaxf(mx[1], m[1]);
          mx[2] = fmaxf(mx[2], m[2]); mx[3] = fmaxf(mx[3], m[3]);
        }
      }
      _Float16* op = pooled + tcur * FLAT_ + q * 1024 + py * 16 + px;
      op[0]   = (_Float16)fmaxf(mx[0], 0.0f);
      op[256] = (_Float16)fmaxf(mx[1], 0.0f);
      op[512] = (_Float16)fmaxf(mx[2], 0.0f);
      op[768] = (_Float16)fmaxf(mx[3], 0.0f);
    }
  }
}

// ---------------------------------------------------------------------------
// K2: per-type linear via fp16 MFMA 16x16x32. Grid = 68 types x 16 f-chunks.
// Writes DETERMINISTIC partials, layout part[t][fc][64] fp32.
// ---------------------------------------------------------------------------
__global__ __launch_bounds__(256) void lin1_mfma_kernel(
    const _Float16* __restrict__ pooled, const float* __restrict__ lin1_w,
    float* __restrict__ part) {
  const int n   = blockIdx.x >> 4;
  const int fc  = blockIdx.x & 15;
  const int tid = threadIdx.x;
  const int wave = tid >> 6, lane = tid & 63;
  const int q = lane >> 4, lr = lane & 15;

  __shared__ __align__(16) _Float16 As[128 * 72];  // 128 rows x 64 k, pitch 72
  __shared__ __align__(16) _Float16 Bt[64 * 72];   // 64 outs x 64 k

  floatx4 acc[2][4];
  #pragma unroll
  for (int mt = 0; mt < 2; mt++)
    #pragma unroll
    for (int nt = 0; nt < 4; nt++)
      acc[mt][nt] = (floatx4){0.f, 0.f, 0.f, 0.f};

  const int f_base = fc * 256;
  for (int step = 0; step < 4; step++) {
    const int f0 = f_base + step * 64;

    // stage A: 128 rows x 64 fp16; 1024 16B-chunks, 4/thread
    #pragma unroll
    for (int j = 0; j < 4; j++) {
      int idx = tid + j * 256;
      int r = idx >> 3, ch = idx & 7;
      uint4 v = *(const uint4*)&pooled[(size_t)(r * N_ + n) * FLAT_ + f0 + ch * 8];
      *(uint4*)&As[r * 72 + ch * 8] = v;
    }
    // stage B: w slice [64 k][64 o]; cvt fp32->fp16 + transpose via half2 packs
    const float* wg = &lin1_w[(size_t)n * (FLAT_ * FD_) + (size_t)f0 * FD_];
    #pragma unroll
    for (int it = 0; it < 2; it++) {
      int p = tid + it * 256;            // 512 (k-pair, o-quad) units
      int o0 = (p & 15) * 4, k0 = (p >> 4) * 2;
      const float* wgk = wg + k0 * 64 + o0;
      float4 va = *(const float4*)wgk;
      float4 vb = *(const float4*)(wgk + 64);
      *(half2v*)&Bt[(o0 + 0) * 72 + k0] = (half2v){(_Float16)va.x, (_Float16)vb.x};
      *(half2v*)&Bt[(o0 + 1) * 72 + k0] = (half2v){(_Float16)va.y, (_Float16)vb.y};
      *(half2v*)&Bt[(o0 + 2) * 72 + k0] = (half2v){(_Float16)va.z, (_Float16)vb.z};
      *(half2v*)&Bt[(o0 + 3) * 72 + k0] = (half2v){(_Float16)va.w, (_Float16)vb.w};
    }
    __syncthreads();

    #pragma unroll
    for (int kh = 0; kh < 2; kh++) {
      half8 af[2], bf[4];
      #pragma unroll
      for (int mt = 0; mt < 2; mt++)
        af[mt] = *(const half8*)&As[(wave * 32 + mt * 16 + lr) * 72 + kh * 32 + q * 8];
      #pragma unroll
      for (int nt = 0; nt < 4; nt++)
        bf[nt] = *(const half8*)&Bt[(nt * 16 + lr) * 72 + kh * 32 + q * 8];
      #pragma unroll
      for (int mt = 0; mt < 2; mt++)
        #pragma unroll
        for (int nt = 0; nt < 4; nt++)
          acc[mt][nt] = __builtin_amdgcn_mfma_f32_16x16x32_f16(
              af[mt], bf[nt], acc[mt][nt], 0, 0, 0);
    }
    __syncthreads();
  }

  // store partials: part[t][fc][64]; D layout col=lane&15, row=quad*4+reg
  #pragma unroll
  for (int mt = 0; mt < 2; mt++) {
    #pragma unroll
    for (int v = 0; v < 4; v++) {
      int r = wave * 32 + mt * 16 + q * 4 + v;
      size_t base = ((size_t)(r * N_ + n) * FCH_ + fc) * FD_;
      #pragma unroll
      for (int nt = 0; nt < 4; nt++)
        part[base + nt * 16 + lr] = acc[mt][nt][v];
    }
  }
}

// ---------------------------------------------------------------------------
// K3a: feats = relu(sum of 16 partials + lin1_b). Grid 544x256, float4/thread.
// part layout [t][fc][64]: per-thread 16 reads at 256 B stride, coalesced.
// ---------------------------------------------------------------------------
__global__ __launch_bounds__(256) void feats_kernel(
    const float* __restrict__ part, const float* __restrict__ lin1_b,
    float* __restrict__ feats) {
  int gid = blockIdx.x * 256 + threadIdx.x;      // T*64/4 = 139264 float4
  int t = gid >> 4, f4 = (gid & 15) * 4;
  int n = t % N_;
  const float* pp = &part[(size_t)t * FCH_ * FD_ + f4];
  float4 s = *(const float4*)&lin1_b[n * FD_ + f4];
  #pragma unroll
  for (int fc = 0; fc < FCH_; fc++) {
    float4 v = *(const float4*)&pp[fc * FD_];
    s.x += v.x; s.y += v.y; s.z += v.z; s.w += v.w;
  }
  s.x = fmaxf(s.x, 0.f); s.y = fmaxf(s.y, 0.f);
  s.z = fmaxf(s.z, 0.f); s.w = fmaxf(s.w, 0.f);
  *(float4*)&feats[(size_t)t * FD_ + f4] = s;
}

// ---------------------------------------------------------------------------
// K3b: GCN aggregation, block = (graph, f-half of 32). 256 blocks x 256 thr.
// Edges + norms staged in LDS; scatter with LDS atomics (conflict-free banks).
// ---------------------------------------------------------------------------
__global__ __launch_bounds__(256) void gcn_agg_kernel(
    const float* __restrict__ feats, const int* __restrict__ edge_index,
    float* __restrict__ agg) {
  const int b  = blockIdx.x >> 1;
  const int fh = blockIdx.x & 1;        // f0 = fh*32
  const int tid = threadIdx.x;

  __shared__ float fS[N_ * 33], aS[N_ * 33];
  __shared__ int   esrcS[EG_], edstS[EG_];
  __shared__ float nrmS[EG_];
  __shared__ int   degS[N_];
  __shared__ float disS[N_];

  if (tid < N_) degS[tid] = 0;
  const int* srcp = edge_index;
  const int* dstp = edge_index + (B_ * EG_);
  const int e0 = b * EG_, nbase = b * N_;
  for (int e = tid; e < EG_; e += 256) {
    esrcS[e] = srcp[e0 + e] - nbase;
    edstS[e] = dstp[e0 + e] - nbase;
  }
  for (int idx = tid; idx < N_ * 32; idx += 256) {
    int i = idx >> 5, f = idx & 31;
    fS[i * 33 + f] = feats[(size_t)(b * N_ + i) * FD_ + fh * 32 + f];
  }
  __syncthreads();
  for (int e = tid; e < EG_; e += 256) atomicAdd(&degS[edstS[e]], 1);
  __syncthreads();
  if (tid < N_) disS[tid] = rsqrtf((float)(degS[tid] + 1));   // +1 self-loop
  __syncthreads();
  for (int e = tid; e < EG_; e += 256)
    nrmS[e] = disS[esrcS[e]] * disS[edstS[e]];
  for (int idx = tid; idx < N_ * 32; idx += 256) {
    int i = idx >> 5, f = idx & 31;
    float d = disS[i];
    aS[i * 33 + f] = d * d * fS[i * 33 + f];
  }
  __syncthreads();
  for (int idx = tid; idx < EG_ * 32; idx += 256) {
    int e = idx >> 5, f = idx & 31;
    atomicAdd(&aS[edstS[e] * 33 + f], nrmS[e] * fS[esrcS[e] * 33 + f]);
  }
  __syncthreads();
  for (int idx = tid; idx < N_ * 32; idx += 256) {
    int i = idx >> 5, f = idx & 31;
    agg[(size_t)(b * N_ + i) * FD_ + fh * 32 + f] = aS[i * 33 + f];
  }
}

// ---------------------------------------------------------------------------
// K3c: per-graph GEMM [68,64]@[64,128] + gcn_b + relu + mean-pool + MLP head.
// 128 blocks x 512 threads; w column hoisted to VGPRs (conflict-free reads).
// ---------------------------------------------------------------------------
__global__ __launch_bounds__(512) void gcn_head_kernel(
    const float* __restrict__ agg, const float* __restrict__ gcn_w,
    const float* __restrict__ gcn_b, const float* __restrict__ w1,
    const float* __restrict__ b1, const float* __restrict__ w2,
    const float* __restrict__ b2, float* __restrict__ out) {
  const int b = blockIdx.x;
  const int tid = threadIdx.x;

  __shared__ float aS[N_ * 68];      // [68][64] pitch 68
  __shared__ float wS[FD_ * GH_];    // 32 KB
  __shared__ float gP[4][GH_];
  __shared__ float z1S[64];

  for (int i4 = tid; i4 < N_ * 16; i4 += 512) {
    int i = i4 >> 4, qf = (i4 & 15) * 4;
    *(float4*)&aS[i * 68 + qf] = *(const float4*)&agg[(size_t)(b * N_ + i) * FD_ + qf];
  }
  #pragma unroll
  for (int j = 0; j < 4; j++)
    ((float4*)wS)[tid + j * 512] = ((const float4*)gcn_w)[tid + j * 512];
  __syncthreads();

  const int j = tid & 127, ig = tid >> 7;
  float wc[64];
  #pragma unroll
  for (int k = 0; k < 64; k++) wc[k] = wS[k * GH_ + j];
  const float bias = gcn_b[j];
  float gsum = 0.f;
  for (int i = ig; i < N_; i += 4) {
    float acc = bias;
    #pragma unroll
    for (int kq = 0; kq < 16; kq++) {
      float4 a = *(const float4*)&aS[i * 68 + kq * 4];   // broadcast
      acc += a.x * wc[kq * 4] + a.y * wc[kq * 4 + 1]
           + a.z * wc[kq * 4 + 2] + a.w * wc[kq * 4 + 3];
    }
    gsum += fmaxf(acc, 0.f);
  }
  gP[ig][j] = gsum;
  __syncthreads();
  if (tid < GH_)
    gP[0][tid] = (gP[0][tid] + gP[1][tid] + gP[2][tid] + gP[3][tid]) * (1.f / 68.f);
  __syncthreads();
  if (tid < 64) {
    float s = b1[tid];
    #pragma unroll 8
    for (int jj = 0; jj < GH_; jj++) s += gP[0][jj] * w1[jj * 64 + tid];
    z1S[tid] = fmaxf(s, 0.f);
  }
  __syncthreads();
  if (tid < 2) {
    float s = b2[tid];
    #pragma unroll 8
    for (int jj = 0; jj < 64; jj++) s += z1S[jj] * w2[jj * 2 + tid];
    out[b * 2 + tid] = s;
  }
}

// ---------------------------------------------------------------------------
extern "C" void kernel_launch(void* const* d_in, const int* in_sizes, int n_in,
                              void* d_out, int out_size, void* d_ws, size_t ws_size,
                              hipStream_t stream) {
  const float* x        = (const float*)d_in[0];
  const int*   edge_idx = (const int*)d_in[1];
  // d_in[2] = batch (layout known: t -> t/N), unused
  const float* conv_w   = (const float*)d_in[3];
  const float* conv_b   = (const float*)d_in[4];
  const float* lin1_w   = (const float*)d_in[5];
  const float* lin1_b   = (const float*)d_in[6];
  const float* gcn_w    = (const float*)d_in[7];
  const float* gcn_b    = (const float*)d_in[8];
  const float* mlp_w1   = (const float*)d_in[9];
  const float* mlp_b1   = (const float*)d_in[10];
  const float* mlp_w2   = (const float*)d_in[11];
  const float* mlp_b2   = (const float*)d_in[12];
  float* outp = (float*)d_out;

  char* wsb = (char*)d_ws;
  _Float16* pooled = (_Float16*)wsb;                               // 71.3 MB
  float* part  = (float*)(wsb + (size_t)T_ * FLAT_ * 2);           // 35.7 MB
  float* feats = part + (size_t)T_ * FCH_ * FD_;                   //  2.2 MB
  float* agg   = feats + (size_t)T_ * FD_;                         //  2.2 MB
  _Float16* wfrag = (_Float16*)(agg + (size_t)T_ * FD_);           //  0.27 MB

  wfrag_prep_kernel<<<N_, 256, 0, stream>>>(conv_w, wfrag);
  conv_pool_kernel<<<HT_, 256, 0, stream>>>(x, wfrag, conv_b, pooled);
  lin1_mfma_kernel<<<N_ * FCH_, 256, 0, stream>>>(pooled, lin1_w, part);
  feats_kernel<<<544, 256, 0, stream>>>(part, lin1_b, feats);
  gcn_agg_kernel<<<B_ * 2, 256, 0, stream>>>(feats, edge_idx, agg);
  gcn_head_kernel<<<B_, 512, 0, stream>>>(agg, gcn_w, gcn_b,
                                          mlp_w1, mlp_b1, mlp_w2, mlp_b2, outp);
}

// Round 7
// 316.226 us; speedup vs baseline: 1.0371x; 1.0034x over previous
//
#include <hip/hip_runtime.h>
#include <hip/hip_fp16.h>

// Problem constants
#define B_   128
#define N_   68
#define C_   3
#define P_   32
#define K_   16
#define FD_  64
#define GH_  128
#define EG_  544          // 8*N
#define T_   8704         // B*N
#define FLAT_ 4096        // K*16*16
#define FCH_ 16           // f-chunks in lin1 (K-split of 256)

typedef __attribute__((ext_vector_type(8))) _Float16 half8;
typedef __attribute__((ext_vector_type(4))) _Float16 half4v;
typedef __attribute__((ext_vector_type(2))) _Float16 half2v;
typedef __attribute__((ext_vector_type(4))) float   floatx4;
typedef __attribute__((ext_vector_type(4))) unsigned int uint32x4;

// LDS image pitches chosen for bank-conflict-free MFMA B-fragment reads:
// row pitch 40 halves (20 dwords), channel pitch 1400 halves (700 dwords).
#define ROWP 40
#define CHP  1400

// ---------------------------------------------------------------------------
// K0: weight-fragment prep (once per node type, not per block).
// wfrag layout: [n][sx][type][k][slot32] halves; type 0 = main, 1 = corr.
// ---------------------------------------------------------------------------
__global__ __launch_bounds__(256) void wfrag_prep_kernel(
    const float* __restrict__ conv_w, _Float16* __restrict__ wfrag) {
  const int n = blockIdx.x;
  const int tid = threadIdx.x;
  const float* wp = conv_w + (size_t)n * (K_ * 27);
  _Float16* out = wfrag + (size_t)n * 2048;
  for (int i = tid; i < 2048; i += 256) {
    int sx   = (i >> 10) & 1;
    int type = (i >> 9) & 1;
    int k    = (i >> 5) & 15;
    int slot = i & 31;
    float v = 0.0f;
    if (type == 0) {
      int q = slot >> 3, r = (slot >> 2) & 1, col = slot & 3;
      int cr = q * 2 + r, c = cr / 3, dy = cr - c * 3, dx = col - sx;
      if (dx >= 0 && dx < 3) v = wp[k * 27 + c * 9 + dy * 3 + dx];
    } else {
      int q = slot >> 3, j = slot & 7;
      if (q == 0 && j < 4) {
        int dx = j - sx;
        if (dx >= 0 && dx < 3) v = wp[k * 27 + 24 + dx];  // c2,dy2 row
      }
    }
    out[i] = (_Float16)v;
  }
}

// ---------------------------------------------------------------------------
// K1: per-node conv3x3(SAME)+bias+relu+maxpool2x2 -> pooled[T][4096] fp16.
// Single image per block (R4 config: 8.4 KB LDS, 8 blocks/CU). Fragments
// loaded from wfrag (coalesced 16B global, L2-hit), issued before the barrier.
// ---------------------------------------------------------------------------
__global__ __launch_bounds__(256) void conv_pool_kernel(
    const float* __restrict__ x, const _Float16* __restrict__ wfrag,
    const float* __restrict__ conv_b, _Float16* __restrict__ pooled) {
  const int t = blockIdx.x;
  const int n = t % N_;
  const int tid = threadIdx.x;

  __shared__ _Float16 xsh[3 * CHP];   // [c][34 rows x pitch 40] fp16

  const int lane = tid & 63;
  const int lr = lane & 15, q = lane >> 4;
  const int wave = tid >> 6;
  const int ldy = lr >> 3, ldx = lr & 7;

  // ---- issue x loads ----
  const float4* xg = (const float4*)(x + (size_t)t * (C_ * P_ * P_));
  float4 xv[3];
  #pragma unroll
  for (int j = 0; j < 3; j++) xv[j] = xg[tid + j * 256];

  // ---- fragment loads (independent of LDS; in flight during staging) ----
  const _Float16* wf = wfrag + (size_t)n * 2048 + lr * 32 + q * 8;
  half8 aMain0 = *(const half8*)&wf[0 * 512];   // sx0 main
  half8 aCorr0 = *(const half8*)&wf[1 * 512];   // sx0 corr
  half8 aMain1 = *(const half8*)&wf[2 * 512];   // sx1 main
  half8 aCorr1 = *(const half8*)&wf[3 * 512];   // sx1 corr
  floatx4 cbias = *(const floatx4*)&conv_b[(size_t)n * K_ + q * 4];

  // ---- zero the 1-wide border ----
  for (int i = tid; i < 396; i += 256) {
    int c = i / 132, j = i - c * 132;
    int off;
    if (j < 34)       off = j;                         // top row
    else if (j < 68)  off = 33 * ROWP + (j - 34);      // bottom row
    else if (j < 100) off = (j - 68 + 1) * ROWP;       // left col
    else              off = (j - 100 + 1) * ROWP + 33; // right col
    xsh[c * CHP + off] = (_Float16)0.0f;
  }
  // ---- interior: cvt fp32->fp16 ----
  #pragma unroll
  for (int j = 0; j < 3; j++) {
    int f0 = (tid + j * 256) * 4;
    int c = f0 >> 10, rem = f0 & 1023, y = rem >> 5, xc = rem & 31;
    _Float16* dp = &xsh[c * CHP + (y + 1) * ROWP + xc + 1];
    dp[0] = (_Float16)xv[j].x; dp[1] = (_Float16)xv[j].y;
    dp[2] = (_Float16)xv[j].z; dp[3] = (_Float16)xv[j].w;
  }
  __syncthreads();

  // per-lane chunk-row base pointers (chunk-rows cr = 2q, 2q+1)
  const int crL = q * 2, crH = crL + 1;
  const int cL = crL / 3, dyL = crL - cL * 3;
  const int cH = crH / 3, dyH = crH - cH * 3;
  const _Float16* chL = &xsh[cL * CHP + dyL * ROWP];
  const _Float16* chH = &xsh[cH * CHP + dyH * ROWP];
  const _Float16* chC = &xsh[2 * CHP + 2 * ROWP];

  #pragma unroll
  for (int i = 0; i < 4; i++) {
    const int qq = wave * 4 + i;
    const int py0 = (qq >> 1) * 2, px0 = (qq & 1) * 8;
    const int py = py0 + ldy, px = px0 + ldx;
    const int ebase = py * (2 * ROWP) + px * 2;
    const _Float16* pL = chL + ebase;
    const _Float16* pH = chH + ebase;
    const _Float16* pC = chC + ebase;

    floatx4 mx;
    #pragma unroll
    for (int sy = 0; sy < 2; sy++) {
      unsigned int uL0 = *(const unsigned int*)&pL[sy * ROWP];
      unsigned int uL1 = *(const unsigned int*)&pL[sy * ROWP + 2];
      unsigned int uH0 = *(const unsigned int*)&pH[sy * ROWP];
      unsigned int uH1 = *(const unsigned int*)&pH[sy * ROWP + 2];
      unsigned int uC0 = *(const unsigned int*)&pC[sy * ROWP];
      unsigned int uC1 = *(const unsigned int*)&pC[sy * ROWP + 2];
      half8 bMain = __builtin_bit_cast(half8, (uint32x4){uL0, uL1, uH0, uH1});
      half8 bCorr = __builtin_bit_cast(half8, (uint32x4){uC0, uC1, uC0, uC1});
      floatx4 d0 = __builtin_amdgcn_mfma_f32_16x16x32_f16(aCorr0, bCorr, cbias, 0, 0, 0);
      d0 = __builtin_amdgcn_mfma_f32_16x16x32_f16(aMain0, bMain, d0, 0, 0, 0);
      floatx4 d1 = __builtin_amdgcn_mfma_f32_16x16x32_f16(aCorr1, bCorr, cbias, 0, 0, 0);
      d1 = __builtin_amdgcn_mfma_f32_16x16x32_f16(aMain1, bMain, d1, 0, 0, 0);
      floatx4 m;
      m[0] = fmaxf(d0[0], d1[0]); m[1] = fmaxf(d0[1], d1[1]);
      m[2] = fmaxf(d0[2], d1[2]); m[3] = fmaxf(d0[3], d1[3]);
      if (sy == 0) mx = m;
      else {
        mx[0] = fmaxf(mx[0], m[0]); mx[1] = fmaxf(mx[1], m[1]);
        mx[2] = fmaxf(mx[2], m[2]); mx[3] = fmaxf(mx[3], m[3]);
      }
    }
    _Float16* op = pooled + (size_t)t * FLAT_ + q * 1024 + py * 16 + px;
    op[0]   = (_Float16)fmaxf(mx[0], 0.0f);
    op[256] = (_Float16)fmaxf(mx[1], 0.0f);
    op[512] = (_Float16)fmaxf(mx[2], 0.0f);
    op[768] = (_Float16)fmaxf(mx[3], 0.0f);
  }
}

// ---------------------------------------------------------------------------
// K2: per-type linear via fp16 MFMA 16x16x32. Grid = 68 types x 16 f-chunks.
// Reg-staged pipeline: step k+1's global loads issued between LDS write and
// barrier, hiding HBM latency under the MFMA phase. Partials stored FP16,
// layout part[t][fc][64] (deterministic; contiguous per node for the tail).
// ---------------------------------------------------------------------------
__global__ __launch_bounds__(256) void lin1_mfma_kernel(
    const _Float16* __restrict__ pooled, const float* __restrict__ lin1_w,
    _Float16* __restrict__ part) {
  const int n   = blockIdx.x >> 4;
  const int fc  = blockIdx.x & 15;
  const int tid = threadIdx.x;
  const int wave = tid >> 6, lane = tid & 63;
  const int q = lane >> 4, lr = lane & 15;

  __shared__ __align__(16) _Float16 As[128 * 72];  // 128 rows x 64 k, pitch 72
  __shared__ __align__(16) _Float16 Bt[64 * 72];   // 64 outs x 64 k

  floatx4 acc[2][4];
  #pragma unroll
  for (int mt = 0; mt < 2; mt++)
    #pragma unroll
    for (int nt = 0; nt < 4; nt++)
      acc[mt][nt] = (floatx4){0.f, 0.f, 0.f, 0.f};

  const int f_base = fc * 256;
  const float* wg = &lin1_w[(size_t)n * (FLAT_ * FD_)];

  // per-thread staging indices
  const int Ab = tid >> 3, Ach8 = (tid & 7) * 8;   // A: row base, k-chunk
  const int o0 = (tid & 15) * 4;                   // B: out quad
  const int k0a = (tid >> 4) * 2;                  // B it=0 k-pair
  const int k0b = k0a + 32;                        // B it=1 k-pair

  uint4 aR[4];
  float4 vaR[2], vbR[2];

#define L1_LOADA(step_) { const int f0 = f_base + (step_) * 64;               \
    _Pragma("unroll")                                                         \
    for (int j = 0; j < 4; j++)                                               \
      aR[j] = *(const uint4*)&pooled[(size_t)((Ab + j * 32) * N_ + n) * FLAT_ \
                                     + f0 + Ach8]; }
#define L1_LOADB(step_) { const int f0 = f_base + (step_) * 64;               \
    const float* wgk0 = wg + (size_t)f0 * FD_ + k0a * 64 + o0;                \
    vaR[0] = *(const float4*)wgk0; vbR[0] = *(const float4*)(wgk0 + 64);      \
    const float* wgk1 = wg + (size_t)f0 * FD_ + k0b * 64 + o0;                \
    vaR[1] = *(const float4*)wgk1; vbR[1] = *(const float4*)(wgk1 + 64); }

  L1_LOADA(0); L1_LOADB(0);

  for (int step = 0; step < 4; step++) {
    if (step) __syncthreads();        // prev MFMA done reading LDS
    // LDS writes from regs
    #pragma unroll
    for (int j = 0; j < 4; j++)
      *(uint4*)&As[(Ab + j * 32) * 72 + Ach8] = aR[j];
    #pragma unroll
    for (int it = 0; it < 2; it++) {
      const int kk = it ? k0b : k0a;
      const float4 va = vaR[it], vb = vbR[it];
      *(half2v*)&Bt[(o0 + 0) * 72 + kk] = (half2v){(_Float16)va.x, (_Float16)vb.x};
      *(half2v*)&Bt[(o0 + 1) * 72 + kk] = (half2v){(_Float16)va.y, (_Float16)vb.y};
      *(half2v*)&Bt[(o0 + 2) * 72 + kk] = (half2v){(_Float16)va.z, (_Float16)vb.z};
      *(half2v*)&Bt[(o0 + 3) * 72 + kk] = (half2v){(_Float16)va.w, (_Float16)vb.w};
    }
    // issue next step's loads (in flight across barrier + MFMA)
    if (step < 3) { L1_LOADA(step + 1); L1_LOADB(step + 1); }
    __syncthreads();

    #pragma unroll
    for (int kh = 0; kh < 2; kh++) {
      half8 af[2], bf[4];
      #pragma unroll
      for (int mt = 0; mt < 2; mt++)
        af[mt] = *(const half8*)&As[(wave * 32 + mt * 16 + lr) * 72 + kh * 32 + q * 8];
      #pragma unroll
      for (int nt = 0; nt < 4; nt++)
        bf[nt] = *(const half8*)&Bt[(nt * 16 + lr) * 72 + kh * 32 + q * 8];
      #pragma unroll
      for (int mt = 0; mt < 2; mt++)
        #pragma unroll
        for (int nt = 0; nt < 4; nt++)
          acc[mt][nt] = __builtin_amdgcn_mfma_f32_16x16x32_f16(
              af[mt], bf[nt], acc[mt][nt], 0, 0, 0);
    }
  }
#undef L1_LOADA
#undef L1_LOADB

  // store partials fp16: part[t][fc][64]; D layout col=lane&15, row=quad*4+reg
  #pragma unroll
  for (int mt = 0; mt < 2; mt++) {
    #pragma unroll
    for (int v = 0; v < 4; v++) {
      int r = wave * 32 + mt * 16 + q * 4 + v;
      size_t base = ((size_t)(r * N_ + n) * FCH_ + fc) * FD_;
      #pragma unroll
      for (int nt = 0; nt < 4; nt++)
        part[base + nt * 16 + lr] = (_Float16)acc[mt][nt][v];
    }
  }
}

// ---------------------------------------------------------------------------
// K3: fused feats+aggregation, block = (graph, f-half of 32). 256 blocks x
// 256 thr. feats = relu(sum16 fp16 partials + lin1_b) computed straight into
// LDS (no global round-trip); then GCN agg with LDS atomics as before.
// ---------------------------------------------------------------------------
__global__ __launch_bounds__(256) void featagg_kernel(
    const _Float16* __restrict__ part, const float* __restrict__ lin1_b,
    const int* __restrict__ edge_index, float* __restrict__ agg) {
  const int b  = blockIdx.x >> 1;
  const int fh = blockIdx.x & 1;        // f0 = fh*32
  const int tid = threadIdx.x;

  __shared__ float fS[N_ * 33], aS[N_ * 33];
  __shared__ int   esrcS[EG_], edstS[EG_];
  __shared__ float nrmS[EG_];
  __shared__ int   degS[N_];
  __shared__ float disS[N_];

  if (tid < N_) degS[tid] = 0;
  const int* srcp = edge_index;
  const int* dstp = edge_index + (B_ * EG_);
  const int e0 = b * EG_, nbase = b * N_;
  for (int e = tid; e < EG_; e += 256) {
    esrcS[e] = srcp[e0 + e] - nbase;
    edstS[e] = dstp[e0 + e] - nbase;
  }
  // feats: unit = (node, f-quad); 16 fc-streams of half4 (64B segments)
  for (int u = tid; u < N_ * 8; u += 256) {
    int i = u >> 3, f4 = (u & 7) * 4;
    const _Float16* pp = &part[((size_t)(b * N_ + i) * FCH_) * FD_ + fh * 32 + f4];
    float4 s = *(const float4*)&lin1_b[i * FD_ + fh * 32 + f4];
    #pragma unroll
    for (int fc = 0; fc < FCH_; fc++) {
      half4v v = *(const half4v*)&pp[fc * FD_];
      s.x += (float)v[0]; s.y += (float)v[1];
      s.z += (float)v[2]; s.w += (float)v[3];
    }
    float* fp = &fS[i * 33 + f4];
    fp[0] = fmaxf(s.x, 0.f); fp[1] = fmaxf(s.y, 0.f);
    fp[2] = fmaxf(s.z, 0.f); fp[3] = fmaxf(s.w, 0.f);
  }
  __syncthreads();
  for (int e = tid; e < EG_; e += 256) atomicAdd(&degS[edstS[e]], 1);
  __syncthreads();
  if (tid < N_) disS[tid] = rsqrtf((float)(degS[tid] + 1));   // +1 self-loop
  __syncthreads();
  for (int e = tid; e < EG_; e += 256)
    nrmS[e] = disS[esrcS[e]] * disS[edstS[e]];
  for (int idx = tid; idx < N_ * 32; idx += 256) {
    int i = idx >> 5, f = idx & 31;
    float d = disS[i];
    aS[i * 33 + f] = d * d * fS[i * 33 + f];
  }
  __syncthreads();
  for (int idx = tid; idx < EG_ * 32; idx += 256) {
    int e = idx >> 5, f = idx & 31;
    atomicAdd(&aS[edstS[e] * 33 + f], nrmS[e] * fS[esrcS[e] * 33 + f]);
  }
  __syncthreads();
  for (int idx = tid; idx < N_ * 32; idx += 256) {
    int i = idx >> 5, f = idx & 31;
    agg[(size_t)(b * N_ + i) * FD_ + fh * 32 + f] = aS[i * 33 + f];
  }
}

// ---------------------------------------------------------------------------
// K4: per-graph GEMM [68,64]@[64,128] + gcn_b + relu + mean-pool + MLP head.
// 128 blocks x 512 threads; w column hoisted to VGPRs (conflict-free reads).
// ---------------------------------------------------------------------------
__global__ __launch_bounds__(512) void gcn_head_kernel(
    const float* __restrict__ agg, const float* __restrict__ gcn_w,
    const float* __restrict__ gcn_b, const float* __restrict__ w1,
    const float* __restrict__ b1, const float* __restrict__ w2,
    const float* __restrict__ b2, float* __restrict__ out) {
  const int b = blockIdx.x;
  const int tid = threadIdx.x;

  __shared__ float aS[N_ * 68];      // [68][64] pitch 68
  __shared__ float wS[FD_ * GH_];    // 32 KB
  __shared__ float gP[4][GH_];
  __shared__ float z1S[64];

  for (int i4 = tid; i4 < N_ * 16; i4 += 512) {
    int i = i4 >> 4, qf = (i4 & 15) * 4;
    *(float4*)&aS[i * 68 + qf] = *(const float4*)&agg[(size_t)(b * N_ + i) * FD_ + qf];
  }
  #pragma unroll
  for (int j = 0; j < 4; j++)
    ((float4*)wS)[tid + j * 512] = ((const float4*)gcn_w)[tid + j * 512];
  __syncthreads();

  const int j = tid & 127, ig = tid >> 7;
  float wc[64];
  #pragma unroll
  for (int k = 0; k < 64; k++) wc[k] = wS[k * GH_ + j];
  const float bias = gcn_b[j];
  float gsum = 0.f;
  for (int i = ig; i < N_; i += 4) {
    float acc = bias;
    #pragma unroll
    for (int kq = 0; kq < 16; kq++) {
      float4 a = *(const float4*)&aS[i * 68 + kq * 4];   // broadcast
      acc += a.x * wc[kq * 4] + a.y * wc[kq * 4 + 1]
           + a.z * wc[kq * 4 + 2] + a.w * wc[kq * 4 + 3];
    }
    gsum += fmaxf(acc, 0.f);
  }
  gP[ig][j] = gsum;
  __syncthreads();
  if (tid < GH_)
    gP[0][tid] = (gP[0][tid] + gP[1][tid] + gP[2][tid] + gP[3][tid]) * (1.f / 68.f);
  __syncthreads();
  if (tid < 64) {
    float s = b1[tid];
    #pragma unroll 8
    for (int jj = 0; jj < GH_; jj++) s += gP[0][jj] * w1[jj * 64 + tid];
    z1S[tid] = fmaxf(s, 0.f);
  }
  __syncthreads();
  if (tid < 2) {
    float s = b2[tid];
    #pragma unroll 8
    for (int jj = 0; jj < 64; jj++) s += z1S[jj] * w2[jj * 2 + tid];
    out[b * 2 + tid] = s;
  }
}

// ---------------------------------------------------------------------------
extern "C" void kernel_launch(void* const* d_in, const int* in_sizes, int n_in,
                              void* d_out, int out_size, void* d_ws, size_t ws_size,
                              hipStream_t stream) {
  const float* x        = (const float*)d_in[0];
  const int*   edge_idx = (const int*)d_in[1];
  // d_in[2] = batch (layout known: t -> t/N), unused
  const float* conv_w   = (const float*)d_in[3];
  const float* conv_b   = (const float*)d_in[4];
  const float* lin1_w   = (const float*)d_in[5];
  const float* lin1_b   = (const float*)d_in[6];
  const float* gcn_w    = (const float*)d_in[7];
  const float* gcn_b    = (const float*)d_in[8];
  const float* mlp_w1   = (const float*)d_in[9];
  const float* mlp_b1   = (const float*)d_in[10];
  const float* mlp_w2   = (const float*)d_in[11];
  const float* mlp_b2   = (const float*)d_in[12];
  float* outp = (float*)d_out;

  char* wsb = (char*)d_ws;
  _Float16* pooled = (_Float16*)wsb;                               // 71.3 MB
  _Float16* part   = pooled + (size_t)T_ * FLAT_;                  // 17.8 MB fp16
  float* agg       = (float*)(part + (size_t)T_ * FCH_ * FD_);     //  2.2 MB
  _Float16* wfrag  = (_Float16*)(agg + (size_t)T_ * FD_);          //  0.27 MB

  wfrag_prep_kernel<<<N_, 256, 0, stream>>>(conv_w, wfrag);
  conv_pool_kernel<<<T_, 256, 0, stream>>>(x, wfrag, conv_b, pooled);
  lin1_mfma_kernel<<<N_ * FCH_, 256, 0, stream>>>(pooled, lin1_w, part);
  featagg_kernel<<<B_ * 2, 256, 0, stream>>>(part, lin1_b, edge_idx, agg);
  gcn_head_kernel<<<B_, 512, 0, stream>>>(agg, gcn_w, gcn_b,
                                          mlp_w1, mlp_b1, mlp_w2, mlp_b2, outp);
}

// Round 8
// 305.278 us; speedup vs baseline: 1.0743x; 1.0359x over previous
//
#include <hip/hip_runtime.h>
#include <hip/hip_fp16.h>

// Problem constants
#define B_   128
#define N_   68
#define C_   3
#define P_   32
#define K_   16
#define FD_  64
#define GH_  128
#define EG_  544          // 8*N
#define T_   8704         // B*N
#define FLAT_ 4096        // K*16*16
#define FCH_ 16           // f-chunks in lin1 (K-split of 256)

typedef __attribute__((ext_vector_type(8))) _Float16 half8;
typedef __attribute__((ext_vector_type(4))) _Float16 half4v;
typedef __attribute__((ext_vector_type(2))) _Float16 half2v;
typedef __attribute__((ext_vector_type(4))) float   floatx4;
typedef __attribute__((ext_vector_type(4))) unsigned int uint32x4;

// LDS image pitches chosen for bank-conflict-free MFMA B-fragment reads:
// row pitch 40 halves (20 dwords), channel pitch 1400 halves (700 dwords).
#define ROWP 40
#define CHP  1400

// pooled layout: [t][spatial s=py*16+px][k]  (k contiguous -> packed stores;
// lin1 B-row mapping f_old = k*256 + s absorbs the permutation exactly)

// ---------------------------------------------------------------------------
// K0: weight-fragment prep (once per node type, not per block).
// wfrag layout: [n][sx][type][k][slot32] halves; type 0 = main, 1 = corr.
// ---------------------------------------------------------------------------
__global__ __launch_bounds__(256) void wfrag_prep_kernel(
    const float* __restrict__ conv_w, _Float16* __restrict__ wfrag) {
  const int n = blockIdx.x;
  const int tid = threadIdx.x;
  const float* wp = conv_w + (size_t)n * (K_ * 27);
  _Float16* out = wfrag + (size_t)n * 2048;
  for (int i = tid; i < 2048; i += 256) {
    int sx   = (i >> 10) & 1;
    int type = (i >> 9) & 1;
    int k    = (i >> 5) & 15;
    int slot = i & 31;
    float v = 0.0f;
    if (type == 0) {
      int q = slot >> 3, r = (slot >> 2) & 1, col = slot & 3;
      int cr = q * 2 + r, c = cr / 3, dy = cr - c * 3, dx = col - sx;
      if (dx >= 0 && dx < 3) v = wp[k * 27 + c * 9 + dy * 3 + dx];
    } else {
      int q = slot >> 3, j = slot & 7;
      if (q == 0 && j < 4) {
        int dx = j - sx;
        if (dx >= 0 && dx < 3) v = wp[k * 27 + 24 + dx];  // c2,dy2 row
      }
    }
    out[i] = (_Float16)v;
  }
}

// ---------------------------------------------------------------------------
// K1: per-node conv3x3(SAME)+bias+relu+maxpool2x2 -> pooled[T][256][16] fp16.
// Epilogue: 4 channels contiguous per thread -> 4x 8B packed stores (was 16
// scalar 2B stores); each store instruction covers two dense 256B segments.
// ---------------------------------------------------------------------------
__global__ __launch_bounds__(256) void conv_pool_kernel(
    const float* __restrict__ x, const _Float16* __restrict__ wfrag,
    const float* __restrict__ conv_b, _Float16* __restrict__ pooled) {
  const int t = blockIdx.x;
  const int n = t % N_;
  const int tid = threadIdx.x;

  __shared__ _Float16 xsh[3 * CHP];   // [c][34 rows x pitch 40] fp16

  const int lane = tid & 63;
  const int lr = lane & 15, q = lane >> 4;
  const int wave = tid >> 6;
  const int ldy = lr >> 3, ldx = lr & 7;

  // ---- issue x loads ----
  const float4* xg = (const float4*)(x + (size_t)t * (C_ * P_ * P_));
  float4 xv[3];
  #pragma unroll
  for (int j = 0; j < 3; j++) xv[j] = xg[tid + j * 256];

  // ---- fragment loads (independent of LDS; in flight during staging) ----
  const _Float16* wf = wfrag + (size_t)n * 2048 + lr * 32 + q * 8;
  half8 aMain0 = *(const half8*)&wf[0 * 512];   // sx0 main
  half8 aCorr0 = *(const half8*)&wf[1 * 512];   // sx0 corr
  half8 aMain1 = *(const half8*)&wf[2 * 512];   // sx1 main
  half8 aCorr1 = *(const half8*)&wf[3 * 512];   // sx1 corr
  floatx4 cbias = *(const floatx4*)&conv_b[(size_t)n * K_ + q * 4];

  // ---- zero the 1-wide border ----
  for (int i = tid; i < 396; i += 256) {
    int c = i / 132, j = i - c * 132;
    int off;
    if (j < 34)       off = j;                         // top row
    else if (j < 68)  off = 33 * ROWP + (j - 34);      // bottom row
    else if (j < 100) off = (j - 68 + 1) * ROWP;       // left col
    else              off = (j - 100 + 1) * ROWP + 33; // right col
    xsh[c * CHP + off] = (_Float16)0.0f;
  }
  // ---- interior: cvt fp32->fp16 ----
  #pragma unroll
  for (int j = 0; j < 3; j++) {
    int f0 = (tid + j * 256) * 4;
    int c = f0 >> 10, rem = f0 & 1023, y = rem >> 5, xc = rem & 31;
    _Float16* dp = &xsh[c * CHP + (y + 1) * ROWP + xc + 1];
    dp[0] = (_Float16)xv[j].x; dp[1] = (_Float16)xv[j].y;
    dp[2] = (_Float16)xv[j].z; dp[3] = (_Float16)xv[j].w;
  }
  __syncthreads();

  // per-lane chunk-row base pointers (chunk-rows cr = 2q, 2q+1)
  const int crL = q * 2, crH = crL + 1;
  const int cL = crL / 3, dyL = crL - cL * 3;
  const int cH = crH / 3, dyH = crH - cH * 3;
  const _Float16* chL = &xsh[cL * CHP + dyL * ROWP];
  const _Float16* chH = &xsh[cH * CHP + dyH * ROWP];
  const _Float16* chC = &xsh[2 * CHP + 2 * ROWP];

  #pragma unroll
  for (int i = 0; i < 4; i++) {
    const int qq = wave * 4 + i;
    const int py0 = (qq >> 1) * 2, px0 = (qq & 1) * 8;
    const int py = py0 + ldy, px = px0 + ldx;
    const int ebase = py * (2 * ROWP) + px * 2;
    const _Float16* pL = chL + ebase;
    const _Float16* pH = chH + ebase;
    const _Float16* pC = chC + ebase;

    floatx4 mx;
    #pragma unroll
    for (int sy = 0; sy < 2; sy++) {
      unsigned int uL0 = *(const unsigned int*)&pL[sy * ROWP];
      unsigned int uL1 = *(const unsigned int*)&pL[sy * ROWP + 2];
      unsigned int uH0 = *(const unsigned int*)&pH[sy * ROWP];
      unsigned int uH1 = *(const unsigned int*)&pH[sy * ROWP + 2];
      unsigned int uC0 = *(const unsigned int*)&pC[sy * ROWP];
      unsigned int uC1 = *(const unsigned int*)&pC[sy * ROWP + 2];
      half8 bMain = __builtin_bit_cast(half8, (uint32x4){uL0, uL1, uH0, uH1});
      half8 bCorr = __builtin_bit_cast(half8, (uint32x4){uC0, uC1, uC0, uC1});
      floatx4 d0 = __builtin_amdgcn_mfma_f32_16x16x32_f16(aCorr0, bCorr, cbias, 0, 0, 0);
      d0 = __builtin_amdgcn_mfma_f32_16x16x32_f16(aMain0, bMain, d0, 0, 0, 0);
      floatx4 d1 = __builtin_amdgcn_mfma_f32_16x16x32_f16(aCorr1, bCorr, cbias, 0, 0, 0);
      d1 = __builtin_amdgcn_mfma_f32_16x16x32_f16(aMain1, bMain, d1, 0, 0, 0);
      floatx4 m;
      m[0] = fmaxf(d0[0], d1[0]); m[1] = fmaxf(d0[1], d1[1]);
      m[2] = fmaxf(d0[2], d1[2]); m[3] = fmaxf(d0[3], d1[3]);
      if (sy == 0) mx = m;
      else {
        mx[0] = fmaxf(mx[0], m[0]); mx[1] = fmaxf(mx[1], m[1]);
        mx[2] = fmaxf(mx[2], m[2]); mx[3] = fmaxf(mx[3], m[3]);
      }
    }
    // packed store: pooled[t][s=py*16+px][k=q*4 .. q*4+3]
    half4v hv;
    hv[0] = (_Float16)fmaxf(mx[0], 0.0f);
    hv[1] = (_Float16)fmaxf(mx[1], 0.0f);
    hv[2] = (_Float16)fmaxf(mx[2], 0.0f);
    hv[3] = (_Float16)fmaxf(mx[3], 0.0f);
    *(half4v*)(pooled + (size_t)t * FLAT_ + (py * 16 + px) * 16 + q * 4) = hv;
  }
}

// ---------------------------------------------------------------------------
// K2: per-type linear via fp16 MFMA 16x16x32. Grid = 68 types x 16 f-chunks.
// Simple staging (R4 config — low VGPR, 8 waves/SIMD). New pooled layout is
// absorbed in the B-row index: chunk fc = pooled spatial row py=fc; B row
// kk -> weight row f_old = (kk&15)*256 + (fc*16 + step*4 + (kk>>4)).
// Partials stored FP16, layout part[t][fc][64] (deterministic).
// ---------------------------------------------------------------------------
__global__ __launch_bounds__(256) void lin1_mfma_kernel(
    const _Float16* __restrict__ pooled, const float* __restrict__ lin1_w,
    _Float16* __restrict__ part) {
  const int n   = blockIdx.x >> 4;
  const int fc  = blockIdx.x & 15;
  const int tid = threadIdx.x;
  const int wave = tid >> 6, lane = tid & 63;
  const int q = lane >> 4, lr = lane & 15;

  __shared__ __align__(16) _Float16 As[128 * 72];  // 128 rows x 64 k, pitch 72
  __shared__ __align__(16) _Float16 Bt[64 * 72];   // 64 outs x 64 k

  floatx4 acc[2][4];
  #pragma unroll
  for (int mt = 0; mt < 2; mt++)
    #pragma unroll
    for (int nt = 0; nt < 4; nt++)
      acc[mt][nt] = (floatx4){0.f, 0.f, 0.f, 0.f};

  const int f_base = fc * 256;
  const float* wg = &lin1_w[(size_t)n * (FLAT_ * FD_)];

  for (int step = 0; step < 4; step++) {
    const int f0 = f_base + step * 64;

    // stage A: 128 rows x 64 fp16; 1024 16B-chunks, 4/thread
    #pragma unroll
    for (int j = 0; j < 4; j++) {
      int idx = tid + j * 256;
      int r = idx >> 3, ch = idx & 7;
      uint4 v = *(const uint4*)&pooled[(size_t)(r * N_ + n) * FLAT_ + f0 + ch * 8];
      *(uint4*)&As[r * 72 + ch * 8] = v;
    }
    // stage B: rows kk,kk+1 -> weight rows f_old, f_old+256
    #pragma unroll
    for (int it = 0; it < 2; it++) {
      int p = tid + it * 256;            // 512 (k-pair, o-quad) units
      int o0 = (p & 15) * 4, k0 = (p >> 4) * 2;
      int kch = k0 & 15;                             // channel
      int s   = fc * 16 + step * 4 + (k0 >> 4);      // spatial
      const float* wgk = wg + ((size_t)(kch * 256 + s)) * FD_ + o0;
      float4 va = *(const float4*)wgk;
      float4 vb = *(const float4*)(wgk + 256 * FD_); // channel kch+1
      *(half2v*)&Bt[(o0 + 0) * 72 + k0] = (half2v){(_Float16)va.x, (_Float16)vb.x};
      *(half2v*)&Bt[(o0 + 1) * 72 + k0] = (half2v){(_Float16)va.y, (_Float16)vb.y};
      *(half2v*)&Bt[(o0 + 2) * 72 + k0] = (half2v){(_Float16)va.z, (_Float16)vb.z};
      *(half2v*)&Bt[(o0 + 3) * 72 + k0] = (half2v){(_Float16)va.w, (_Float16)vb.w};
    }
    __syncthreads();

    #pragma unroll
    for (int kh = 0; kh < 2; kh++) {
      half8 af[2], bf[4];
      #pragma unroll
      for (int mt = 0; mt < 2; mt++)
        af[mt] = *(const half8*)&As[(wave * 32 + mt * 16 + lr) * 72 + kh * 32 + q * 8];
      #pragma unroll
      for (int nt = 0; nt < 4; nt++)
        bf[nt] = *(const half8*)&Bt[(nt * 16 + lr) * 72 + kh * 32 + q * 8];
      #pragma unroll
      for (int mt = 0; mt < 2; mt++)
        #pragma unroll
        for (int nt = 0; nt < 4; nt++)
          acc[mt][nt] = __builtin_amdgcn_mfma_f32_16x16x32_f16(
              af[mt], bf[nt], acc[mt][nt], 0, 0, 0);
    }
    __syncthreads();
  }

  // store partials fp16: part[t][fc][64]; D layout col=lane&15, row=quad*4+reg
  #pragma unroll
  for (int mt = 0; mt < 2; mt++) {
    #pragma unroll
    for (int v = 0; v < 4; v++) {
      int r = wave * 32 + mt * 16 + q * 4 + v;
      size_t base = ((size_t)(r * N_ + n) * FCH_ + fc) * FD_;
      #pragma unroll
      for (int nt = 0; nt < 4; nt++)
        part[base + nt * 16 + lr] = (_Float16)acc[mt][nt][v];
    }
  }
}

// ---------------------------------------------------------------------------
// K3a: feats = relu(sum of 16 fp16 partials + lin1_b). Grid 544x256.
// ---------------------------------------------------------------------------
__global__ __launch_bounds__(256) void feats_kernel(
    const _Float16* __restrict__ part, const float* __restrict__ lin1_b,
    float* __restrict__ feats) {
  int gid = blockIdx.x * 256 + threadIdx.x;      // T*64/4 = 139264 quads
  int t = gid >> 4, f4 = (gid & 15) * 4;
  int n = t % N_;
  const _Float16* pp = &part[(size_t)t * FCH_ * FD_ + f4];
  float4 s = *(const float4*)&lin1_b[n * FD_ + f4];
  #pragma unroll
  for (int fc = 0; fc < FCH_; fc++) {
    half4v v = *(const half4v*)&pp[fc * FD_];
    s.x += (float)v[0]; s.y += (float)v[1];
    s.z += (float)v[2]; s.w += (float)v[3];
  }
  s.x = fmaxf(s.x, 0.f); s.y = fmaxf(s.y, 0.f);
  s.z = fmaxf(s.z, 0.f); s.w = fmaxf(s.w, 0.f);
  *(float4*)&feats[(size_t)t * FD_ + f4] = s;
}

// ---------------------------------------------------------------------------
// K3b: GCN aggregation, block = (graph, f-half of 32). 256 blocks x 256 thr.
// Edges + norms staged in LDS; scatter with LDS atomics (conflict-free banks).
// ---------------------------------------------------------------------------
__global__ __launch_bounds__(256) void gcn_agg_kernel(
    const float* __restrict__ feats, const int* __restrict__ edge_index,
    float* __restrict__ agg) {
  const int b  = blockIdx.x >> 1;
  const int fh = blockIdx.x & 1;        // f0 = fh*32
  const int tid = threadIdx.x;

  __shared__ float fS[N_ * 33], aS[N_ * 33];
  __shared__ int   esrcS[EG_], edstS[EG_];
  __shared__ float nrmS[EG_];
  __shared__ int   degS[N_];
  __shared__ float disS[N_];

  if (tid < N_) degS[tid] = 0;
  const int* srcp = edge_index;
  const int* dstp = edge_index + (B_ * EG_);
  const int e0 = b * EG_, nbase = b * N_;
  for (int e = tid; e < EG_; e += 256) {
    esrcS[e] = srcp[e0 + e] - nbase;
    edstS[e] = dstp[e0 + e] - nbase;
  }
  for (int idx = tid; idx < N_ * 32; idx += 256) {
    int i = idx >> 5, f = idx & 31;
    fS[i * 33 + f] = feats[(size_t)(b * N_ + i) * FD_ + fh * 32 + f];
  }
  __syncthreads();
  for (int e = tid; e < EG_; e += 256) atomicAdd(&degS[edstS[e]], 1);
  __syncthreads();
  if (tid < N_) disS[tid] = rsqrtf((float)(degS[tid] + 1));   // +1 self-loop
  __syncthreads();
  for (int e = tid; e < EG_; e += 256)
    nrmS[e] = disS[esrcS[e]] * disS[edstS[e]];
  for (int idx = tid; idx < N_ * 32; idx += 256) {
    int i = idx >> 5, f = idx & 31;
    float d = disS[i];
    aS[i * 33 + f] = d * d * fS[i * 33 + f];
  }
  __syncthreads();
  for (int idx = tid; idx < EG_ * 32; idx += 256) {
    int e = idx >> 5, f = idx & 31;
    atomicAdd(&aS[edstS[e] * 33 + f], nrmS[e] * fS[esrcS[e] * 33 + f]);
  }
  __syncthreads();
  for (int idx = tid; idx < N_ * 32; idx += 256) {
    int i = idx >> 5, f = idx & 31;
    agg[(size_t)(b * N_ + i) * FD_ + fh * 32 + f] = aS[i * 33 + f];
  }
}

// ---------------------------------------------------------------------------
// K3c: per-graph GEMM [68,64]@[64,128] + gcn_b + relu + mean-pool + MLP head.
// 128 blocks x 512 threads; w column hoisted to VGPRs (conflict-free reads).
// ---------------------------------------------------------------------------
__global__ __launch_bounds__(512) void gcn_head_kernel(
    const float* __restrict__ agg, const float* __restrict__ gcn_w,
    const float* __restrict__ gcn_b, const float* __restrict__ w1,
    const float* __restrict__ b1, const float* __restrict__ w2,
    const float* __restrict__ b2, float* __restrict__ out) {
  const int b = blockIdx.x;
  const int tid = threadIdx.x;

  __shared__ float aS[N_ * 68];      // [68][64] pitch 68
  __shared__ float wS[FD_ * GH_];    // 32 KB
  __shared__ float gP[4][GH_];
  __shared__ float z1S[64];

  for (int i4 = tid; i4 < N_ * 16; i4 += 512) {
    int i = i4 >> 4, qf = (i4 & 15) * 4;
    *(float4*)&aS[i * 68 + qf] = *(const float4*)&agg[(size_t)(b * N_ + i) * FD_ + qf];
  }
  #pragma unroll
  for (int j = 0; j < 4; j++)
    ((float4*)wS)[tid + j * 512] = ((const float4*)gcn_w)[tid + j * 512];
  __syncthreads();

  const int j = tid & 127, ig = tid >> 7;
  float wc[64];
  #pragma unroll
  for (int k = 0; k < 64; k++) wc[k] = wS[k * GH_ + j];
  const float bias = gcn_b[j];
  float gsum = 0.f;
  for (int i = ig; i < N_; i += 4) {
    float acc = bias;
    #pragma unroll
    for (int kq = 0; kq < 16; kq++) {
      float4 a = *(const float4*)&aS[i * 68 + kq * 4];   // broadcast
      acc += a.x * wc[kq * 4] + a.y * wc[kq * 4 + 1]
           + a.z * wc[kq * 4 + 2] + a.w * wc[kq * 4 + 3];
    }
    gsum += fmaxf(acc, 0.f);
  }
  gP[ig][j] = gsum;
  __syncthreads();
  if (tid < GH_)
    gP[0][tid] = (gP[0][tid] + gP[1][tid] + gP[2][tid] + gP[3][tid]) * (1.f / 68.f);
  __syncthreads();
  if (tid < 64) {
    float s = b1[tid];
    #pragma unroll 8
    for (int jj = 0; jj < GH_; jj++) s += gP[0][jj] * w1[jj * 64 + tid];
    z1S[tid] = fmaxf(s, 0.f);
  }
  __syncthreads();
  if (tid < 2) {
    float s = b2[tid];
    #pragma unroll 8
    for (int jj = 0; jj < 64; jj++) s += z1S[jj] * w2[jj * 2 + tid];
    out[b * 2 + tid] = s;
  }
}

// ---------------------------------------------------------------------------
extern "C" void kernel_launch(void* const* d_in, const int* in_sizes, int n_in,
                              void* d_out, int out_size, void* d_ws, size_t ws_size,
                              hipStream_t stream) {
  const float* x        = (const float*)d_in[0];
  const int*   edge_idx = (const int*)d_in[1];
  // d_in[2] = batch (layout known: t -> t/N), unused
  const float* conv_w   = (const float*)d_in[3];
  const float* conv_b   = (const float*)d_in[4];
  const float* lin1_w   = (const float*)d_in[5];
  const float* lin1_b   = (const float*)d_in[6];
  const float* gcn_w    = (const float*)d_in[7];
  const float* gcn_b    = (const float*)d_in[8];
  const float* mlp_w1   = (const float*)d_in[9];
  const float* mlp_b1   = (const float*)d_in[10];
  const float* mlp_w2   = (const float*)d_in[11];
  const float* mlp_b2   = (const float*)d_in[12];
  float* outp = (float*)d_out;

  char* wsb = (char*)d_ws;
  _Float16* pooled = (_Float16*)wsb;                               // 71.3 MB
  _Float16* part   = pooled + (size_t)T_ * FLAT_;                  // 17.8 MB fp16
  float* feats     = (float*)(part + (size_t)T_ * FCH_ * FD_);     //  2.2 MB
  float* agg       = feats + (size_t)T_ * FD_;                     //  2.2 MB
  _Float16* wfrag  = (_Float16*)(agg + (size_t)T_ * FD_);          //  0.27 MB

  wfrag_prep_kernel<<<N_, 256, 0, stream>>>(conv_w, wfrag);
  conv_pool_kernel<<<T_, 256, 0, stream>>>(x, wfrag, conv_b, pooled);
  lin1_mfma_kernel<<<N_ * FCH_, 256, 0, stream>>>(pooled, lin1_w, part);
  feats_kernel<<<544, 256, 0, stream>>>(part, lin1_b, feats);
  gcn_agg_kernel<<<B_ * 2, 256, 0, stream>>>(feats, edge_idx, agg);
  gcn_head_kernel<<<B_, 512, 0, stream>>>(agg, gcn_w, gcn_b,
                                          mlp_w1, mlp_b1, mlp_w2, mlp_b2, outp);
}

// Round 9
// 301.066 us; speedup vs baseline: 1.0893x; 1.0140x over previous
//
#include <hip/hip_runtime.h>
#include <hip/hip_fp16.h>

// Problem constants
#define B_   128
#define N_   68
#define C_   3
#define P_   32
#define K_   16
#define FD_  64
#define GH_  128
#define EG_  544          // 8*N
#define T_   8704         // B*N
#define FLAT_ 4096        // K*16*16
#define FCH_ 16           // f-chunks in lin1 (K-split of 256)

typedef __attribute__((ext_vector_type(8))) _Float16 half8;
typedef __attribute__((ext_vector_type(4))) _Float16 half4v;
typedef __attribute__((ext_vector_type(2))) _Float16 half2v;
typedef __attribute__((ext_vector_type(4))) float   floatx4;
typedef __attribute__((ext_vector_type(4))) unsigned int uint32x4;

// LDS image pitches chosen for bank-conflict-free MFMA B-fragment reads:
// row pitch 40 halves (20 dwords), channel pitch 1400 halves (700 dwords).
#define ROWP 40
#define CHP  1400

// pooled layout: [t][spatial s=py*16+px][k]  (k contiguous -> packed stores;
// lin1 B-row mapping f_old = k*256 + s absorbs the permutation exactly)

// ---------------------------------------------------------------------------
// K0: weight-fragment prep (once per node type, not per block).
// wfrag layout: [n][sx][type][k][slot32] halves; type 0 = main, 1 = corr.
// ---------------------------------------------------------------------------
__global__ __launch_bounds__(256) void wfrag_prep_kernel(
    const float* __restrict__ conv_w, _Float16* __restrict__ wfrag) {
  const int n = blockIdx.x;
  const int tid = threadIdx.x;
  const float* wp = conv_w + (size_t)n * (K_ * 27);
  _Float16* out = wfrag + (size_t)n * 2048;
  for (int i = tid; i < 2048; i += 256) {
    int sx   = (i >> 10) & 1;
    int type = (i >> 9) & 1;
    int k    = (i >> 5) & 15;
    int slot = i & 31;
    float v = 0.0f;
    if (type == 0) {
      int q = slot >> 3, r = (slot >> 2) & 1, col = slot & 3;
      int cr = q * 2 + r, c = cr / 3, dy = cr - c * 3, dx = col - sx;
      if (dx >= 0 && dx < 3) v = wp[k * 27 + c * 9 + dy * 3 + dx];
    } else {
      int q = slot >> 3, j = slot & 7;
      if (q == 0 && j < 4) {
        int dx = j - sx;
        if (dx >= 0 && dx < 3) v = wp[k * 27 + 24 + dx];  // c2,dy2 row
      }
    }
    out[i] = (_Float16)v;
  }
}

// ---------------------------------------------------------------------------
// K1: per-node conv3x3(SAME)+bias+relu+maxpool2x2 -> pooled[T][256][16] fp16.
// Epilogue: 4 channels contiguous per thread -> 4x 8B packed stores; each
// store instruction covers two dense 256B segments.
// ---------------------------------------------------------------------------
__global__ __launch_bounds__(256) void conv_pool_kernel(
    const float* __restrict__ x, const _Float16* __restrict__ wfrag,
    const float* __restrict__ conv_b, _Float16* __restrict__ pooled) {
  const int t = blockIdx.x;
  const int n = t % N_;
  const int tid = threadIdx.x;

  __shared__ _Float16 xsh[3 * CHP];   // [c][34 rows x pitch 40] fp16

  const int lane = tid & 63;
  const int lr = lane & 15, q = lane >> 4;
  const int wave = tid >> 6;
  const int ldy = lr >> 3, ldx = lr & 7;

  // ---- issue x loads ----
  const float4* xg = (const float4*)(x + (size_t)t * (C_ * P_ * P_));
  float4 xv[3];
  #pragma unroll
  for (int j = 0; j < 3; j++) xv[j] = xg[tid + j * 256];

  // ---- fragment loads (independent of LDS; in flight during staging) ----
  const _Float16* wf = wfrag + (size_t)n * 2048 + lr * 32 + q * 8;
  half8 aMain0 = *(const half8*)&wf[0 * 512];   // sx0 main
  half8 aCorr0 = *(const half8*)&wf[1 * 512];   // sx0 corr
  half8 aMain1 = *(const half8*)&wf[2 * 512];   // sx1 main
  half8 aCorr1 = *(const half8*)&wf[3 * 512];   // sx1 corr
  floatx4 cbias = *(const floatx4*)&conv_b[(size_t)n * K_ + q * 4];

  // ---- zero the 1-wide border ----
  for (int i = tid; i < 396; i += 256) {
    int c = i / 132, j = i - c * 132;
    int off;
    if (j < 34)       off = j;                         // top row
    else if (j < 68)  off = 33 * ROWP + (j - 34);      // bottom row
    else if (j < 100) off = (j - 68 + 1) * ROWP;       // left col
    else              off = (j - 100 + 1) * ROWP + 33; // right col
    xsh[c * CHP + off] = (_Float16)0.0f;
  }
  // ---- interior: cvt fp32->fp16 ----
  #pragma unroll
  for (int j = 0; j < 3; j++) {
    int f0 = (tid + j * 256) * 4;
    int c = f0 >> 10, rem = f0 & 1023, y = rem >> 5, xc = rem & 31;
    _Float16* dp = &xsh[c * CHP + (y + 1) * ROWP + xc + 1];
    dp[0] = (_Float16)xv[j].x; dp[1] = (_Float16)xv[j].y;
    dp[2] = (_Float16)xv[j].z; dp[3] = (_Float16)xv[j].w;
  }
  __syncthreads();

  // per-lane chunk-row base pointers (chunk-rows cr = 2q, 2q+1)
  const int crL = q * 2, crH = crL + 1;
  const int cL = crL / 3, dyL = crL - cL * 3;
  const int cH = crH / 3, dyH = crH - cH * 3;
  const _Float16* chL = &xsh[cL * CHP + dyL * ROWP];
  const _Float16* chH = &xsh[cH * CHP + dyH * ROWP];
  const _Float16* chC = &xsh[2 * CHP + 2 * ROWP];

  #pragma unroll
  for (int i = 0; i < 4; i++) {
    const int qq = wave * 4 + i;
    const int py0 = (qq >> 1) * 2, px0 = (qq & 1) * 8;
    const int py = py0 + ldy, px = px0 + ldx;
    const int ebase = py * (2 * ROWP) + px * 2;
    const _Float16* pL = chL + ebase;
    const _Float16* pH = chH + ebase;
    const _Float16* pC = chC + ebase;

    floatx4 mx;
    #pragma unroll
    for (int sy = 0; sy < 2; sy++) {
      unsigned int uL0 = *(const unsigned int*)&pL[sy * ROWP];
      unsigned int uL1 = *(const unsigned int*)&pL[sy * ROWP + 2];
      unsigned int uH0 = *(const unsigned int*)&pH[sy * ROWP];
      unsigned int uH1 = *(const unsigned int*)&pH[sy * ROWP + 2];
      unsigned int uC0 = *(const unsigned int*)&pC[sy * ROWP];
      unsigned int uC1 = *(const unsigned int*)&pC[sy * ROWP + 2];
      half8 bMain = __builtin_bit_cast(half8, (uint32x4){uL0, uL1, uH0, uH1});
      half8 bCorr = __builtin_bit_cast(half8, (uint32x4){uC0, uC1, uC0, uC1});
      floatx4 d0 = __builtin_amdgcn_mfma_f32_16x16x32_f16(aCorr0, bCorr, cbias, 0, 0, 0);
      d0 = __builtin_amdgcn_mfma_f32_16x16x32_f16(aMain0, bMain, d0, 0, 0, 0);
      floatx4 d1 = __builtin_amdgcn_mfma_f32_16x16x32_f16(aCorr1, bCorr, cbias, 0, 0, 0);
      d1 = __builtin_amdgcn_mfma_f32_16x16x32_f16(aMain1, bMain, d1, 0, 0, 0);
      floatx4 m;
      m[0] = fmaxf(d0[0], d1[0]); m[1] = fmaxf(d0[1], d1[1]);
      m[2] = fmaxf(d0[2], d1[2]); m[3] = fmaxf(d0[3], d1[3]);
      if (sy == 0) mx = m;
      else {
        mx[0] = fmaxf(mx[0], m[0]); mx[1] = fmaxf(mx[1], m[1]);
        mx[2] = fmaxf(mx[2], m[2]); mx[3] = fmaxf(mx[3], m[3]);
      }
    }
    // packed store: pooled[t][s=py*16+px][k=q*4 .. q*4+3]
    half4v hv;
    hv[0] = (_Float16)fmaxf(mx[0], 0.0f);
    hv[1] = (_Float16)fmaxf(mx[1], 0.0f);
    hv[2] = (_Float16)fmaxf(mx[2], 0.0f);
    hv[3] = (_Float16)fmaxf(mx[3], 0.0f);
    *(half4v*)(pooled + (size_t)t * FLAT_ + (py * 16 + px) * 16 + q * 4) = hv;
  }
}

// ---------------------------------------------------------------------------
// K2: per-type linear via fp16 MFMA 16x16x32. M-SPLIT grid: 68 types x 16
// f-chunks x 2 M-halves = 2176 blocks (8.5/CU; LDS 18.4 KB, 4 waves -> full
// 8-block occupancy for latency hiding). Each block: 64 batch rows x 64 outs,
// K=256 in 4 steps. B slice read twice chip-wide (L3-resident lin1_w).
// Partials stored FP16, layout part[t][fc][64] (deterministic).
// ---------------------------------------------------------------------------
__global__ __launch_bounds__(256) void lin1_mfma_kernel(
    const _Float16* __restrict__ pooled, const float* __restrict__ lin1_w,
    _Float16* __restrict__ part) {
  const int n   = blockIdx.x >> 5;
  const int fc  = (blockIdx.x >> 1) & 15;
  const int mh  = blockIdx.x & 1;       // M-half: rows [mh*64, mh*64+64)
  const int tid = threadIdx.x;
  const int wave = tid >> 6, lane = tid & 63;
  const int q = lane >> 4, lr = lane & 15;

  __shared__ __align__(16) _Float16 As[64 * 72];   // 64 rows x 64 k, pitch 72
  __shared__ __align__(16) _Float16 Bt[64 * 72];   // 64 outs x 64 k

  floatx4 acc[4];
  #pragma unroll
  for (int nt = 0; nt < 4; nt++)
    acc[nt] = (floatx4){0.f, 0.f, 0.f, 0.f};

  const int f_base = fc * 256;
  const int r_base = mh * 64;
  const float* wg = &lin1_w[(size_t)n * (FLAT_ * FD_)];

  for (int step = 0; step < 4; step++) {
    const int f0 = f_base + step * 64;

    // stage A: 64 rows x 64 fp16; 512 16B-chunks, 2/thread
    #pragma unroll
    for (int j = 0; j < 2; j++) {
      int idx = tid + j * 256;
      int r = idx >> 3, ch = idx & 7;
      uint4 v = *(const uint4*)&pooled[(size_t)((r_base + r) * N_ + n) * FLAT_
                                       + f0 + ch * 8];
      *(uint4*)&As[r * 72 + ch * 8] = v;
    }
    // stage B: rows kk,kk+1 -> weight rows f_old, f_old+256
    #pragma unroll
    for (int it = 0; it < 2; it++) {
      int p = tid + it * 256;            // 512 (k-pair, o-quad) units
      int o0 = (p & 15) * 4, k0 = (p >> 4) * 2;
      int kch = k0 & 15;                             // channel
      int s   = fc * 16 + step * 4 + (k0 >> 4);      // spatial
      const float* wgk = wg + ((size_t)(kch * 256 + s)) * FD_ + o0;
      float4 va = *(const float4*)wgk;
      float4 vb = *(const float4*)(wgk + 256 * FD_); // channel kch+1
      *(half2v*)&Bt[(o0 + 0) * 72 + k0] = (half2v){(_Float16)va.x, (_Float16)vb.x};
      *(half2v*)&Bt[(o0 + 1) * 72 + k0] = (half2v){(_Float16)va.y, (_Float16)vb.y};
      *(half2v*)&Bt[(o0 + 2) * 72 + k0] = (half2v){(_Float16)va.z, (_Float16)vb.z};
      *(half2v*)&Bt[(o0 + 3) * 72 + k0] = (half2v){(_Float16)va.w, (_Float16)vb.w};
    }
    __syncthreads();

    #pragma unroll
    for (int kh = 0; kh < 2; kh++) {
      half8 af, bf[4];
      af = *(const half8*)&As[(wave * 16 + lr) * 72 + kh * 32 + q * 8];
      #pragma unroll
      for (int nt = 0; nt < 4; nt++)
        bf[nt] = *(const half8*)&Bt[(nt * 16 + lr) * 72 + kh * 32 + q * 8];
      #pragma unroll
      for (int nt = 0; nt < 4; nt++)
        acc[nt] = __builtin_amdgcn_mfma_f32_16x16x32_f16(af, bf[nt], acc[nt], 0, 0, 0);
    }
    __syncthreads();
  }

  // store partials fp16: part[t][fc][64]; D layout col=lane&15, row=quad*4+reg
  #pragma unroll
  for (int v = 0; v < 4; v++) {
    int r = r_base + wave * 16 + q * 4 + v;
    size_t base = ((size_t)(r * N_ + n) * FCH_ + fc) * FD_;
    #pragma unroll
    for (int nt = 0; nt < 4; nt++)
      part[base + nt * 16 + lr] = (_Float16)acc[nt][v];
  }
}

// ---------------------------------------------------------------------------
// K3a: feats = relu(sum of 16 fp16 partials + lin1_b). Grid 544x256.
// ---------------------------------------------------------------------------
__global__ __launch_bounds__(256) void feats_kernel(
    const _Float16* __restrict__ part, const float* __restrict__ lin1_b,
    float* __restrict__ feats) {
  int gid = blockIdx.x * 256 + threadIdx.x;      // T*64/4 = 139264 quads
  int t = gid >> 4, f4 = (gid & 15) * 4;
  int n = t % N_;
  const _Float16* pp = &part[(size_t)t * FCH_ * FD_ + f4];
  float4 s = *(const float4*)&lin1_b[n * FD_ + f4];
  #pragma unroll
  for (int fc = 0; fc < FCH_; fc++) {
    half4v v = *(const half4v*)&pp[fc * FD_];
    s.x += (float)v[0]; s.y += (float)v[1];
    s.z += (float)v[2]; s.w += (float)v[3];
  }
  s.x = fmaxf(s.x, 0.f); s.y = fmaxf(s.y, 0.f);
  s.z = fmaxf(s.z, 0.f); s.w = fmaxf(s.w, 0.f);
  *(float4*)&feats[(size_t)t * FD_ + f4] = s;
}

// ---------------------------------------------------------------------------
// K3b: GCN aggregation, block = (graph, f-half of 32). 256 blocks x 256 thr.
// Edges + norms staged in LDS; scatter with LDS atomics (conflict-free banks).
// ---------------------------------------------------------------------------
__global__ __launch_bounds__(256) void gcn_agg_kernel(
    const float* __restrict__ feats, const int* __restrict__ edge_index,
    float* __restrict__ agg) {
  const int b  = blockIdx.x >> 1;
  const int fh = blockIdx.x & 1;        // f0 = fh*32
  const int tid = threadIdx.x;

  __shared__ float fS[N_ * 33], aS[N_ * 33];
  __shared__ int   esrcS[EG_], edstS[EG_];
  __shared__ float nrmS[EG_];
  __shared__ int   degS[N_];
  __shared__ float disS[N_];

  if (tid < N_) degS[tid] = 0;
  const int* srcp = edge_index;
  const int* dstp = edge_index + (B_ * EG_);
  const int e0 = b * EG_, nbase = b * N_;
  for (int e = tid; e < EG_; e += 256) {
    esrcS[e] = srcp[e0 + e] - nbase;
    edstS[e] = dstp[e0 + e] - nbase;
  }
  for (int idx = tid; idx < N_ * 32; idx += 256) {
    int i = idx >> 5, f = idx & 31;
    fS[i * 33 + f] = feats[(size_t)(b * N_ + i) * FD_ + fh * 32 + f];
  }
  __syncthreads();
  for (int e = tid; e < EG_; e += 256) atomicAdd(&degS[edstS[e]], 1);
  __syncthreads();
  if (tid < N_) disS[tid] = rsqrtf((float)(degS[tid] + 1));   // +1 self-loop
  __syncthreads();
  for (int e = tid; e < EG_; e += 256)
    nrmS[e] = disS[esrcS[e]] * disS[edstS[e]];
  for (int idx = tid; idx < N_ * 32; idx += 256) {
    int i = idx >> 5, f = idx & 31;
    float d = disS[i];
    aS[i * 33 + f] = d * d * fS[i * 33 + f];
  }
  __syncthreads();
  for (int idx = tid; idx < EG_ * 32; idx += 256) {
    int e = idx >> 5, f = idx & 31;
    atomicAdd(&aS[edstS[e] * 33 + f], nrmS[e] * fS[esrcS[e] * 33 + f]);
  }
  __syncthreads();
  for (int idx = tid; idx < N_ * 32; idx += 256) {
    int i = idx >> 5, f = idx & 31;
    agg[(size_t)(b * N_ + i) * FD_ + fh * 32 + f] = aS[i * 33 + f];
  }
}

// ---------------------------------------------------------------------------
// K3c: per-graph GEMM [68,64]@[64,128] + gcn_b + relu + mean-pool + MLP head.
// 128 blocks x 512 threads; w column hoisted to VGPRs (conflict-free reads).
// ---------------------------------------------------------------------------
__global__ __launch_bounds__(512) void gcn_head_kernel(
    const float* __restrict__ agg, const float* __restrict__ gcn_w,
    const float* __restrict__ gcn_b, const float* __restrict__ w1,
    const float* __restrict__ b1, const float* __restrict__ w2,
    const float* __restrict__ b2, float* __restrict__ out) {
  const int b = blockIdx.x;
  const int tid = threadIdx.x;

  __shared__ float aS[N_ * 68];      // [68][64] pitch 68
  __shared__ float wS[FD_ * GH_];    // 32 KB
  __shared__ float gP[4][GH_];
  __shared__ float z1S[64];

  for (int i4 = tid; i4 < N_ * 16; i4 += 512) {
    int i = i4 >> 4, qf = (i4 & 15) * 4;
    *(float4*)&aS[i * 68 + qf] = *(const float4*)&agg[(size_t)(b * N_ + i) * FD_ + qf];
  }
  #pragma unroll
  for (int j = 0; j < 4; j++)
    ((float4*)wS)[tid + j * 512] = ((const float4*)gcn_w)[tid + j * 512];
  __syncthreads();

  const int j = tid & 127, ig = tid >> 7;
  float wc[64];
  #pragma unroll
  for (int k = 0; k < 64; k++) wc[k] = wS[k * GH_ + j];
  const float bias = gcn_b[j];
  float gsum = 0.f;
  for (int i = ig; i < N_; i += 4) {
    float acc = bias;
    #pragma unroll
    for (int kq = 0; kq < 16; kq++) {
      float4 a = *(const float4*)&aS[i * 68 + kq * 4];   // broadcast
      acc += a.x * wc[kq * 4] + a.y * wc[kq * 4 + 1]
           + a.z * wc[kq * 4 + 2] + a.w * wc[kq * 4 + 3];
    }
    gsum += fmaxf(acc, 0.f);
  }
  gP[ig][j] = gsum;
  __syncthreads();
  if (tid < GH_)
    gP[0][tid] = (gP[0][tid] + gP[1][tid] + gP[2][tid] + gP[3][tid]) * (1.f / 68.f);
  __syncthreads();
  if (tid < 64) {
    float s = b1[tid];
    #pragma unroll 8
    for (int jj = 0; jj < GH_; jj++) s += gP[0][jj] * w1[jj * 64 + tid];
    z1S[tid] = fmaxf(s, 0.f);
  }
  __syncthreads();
  if (tid < 2) {
    float s = b2[tid];
    #pragma unroll 8
    for (int jj = 0; jj < 64; jj++) s += z1S[jj] * w2[jj * 2 + tid];
    out[b * 2 + tid] = s;
  }
}

// ---------------------------------------------------------------------------
extern "C" void kernel_launch(void* const* d_in, const int* in_sizes, int n_in,
                              void* d_out, int out_size, void* d_ws, size_t ws_size,
                              hipStream_t stream) {
  const float* x        = (const float*)d_in[0];
  const int*   edge_idx = (const int*)d_in[1];
  // d_in[2] = batch (layout known: t -> t/N), unused
  const float* conv_w   = (const float*)d_in[3];
  const float* conv_b   = (const float*)d_in[4];
  const float* lin1_w   = (const float*)d_in[5];
  const float* lin1_b   = (const float*)d_in[6];
  const float* gcn_w    = (const float*)d_in[7];
  const float* gcn_b    = (const float*)d_in[8];
  const float* mlp_w1   = (const float*)d_in[9];
  const float* mlp_b1   = (const float*)d_in[10];
  const float* mlp_w2   = (const float*)d_in[11];
  const float* mlp_b2   = (const float*)d_in[12];
  float* outp = (float*)d_out;

  char* wsb = (char*)d_ws;
  _Float16* pooled = (_Float16*)wsb;                               // 71.3 MB
  _Float16* part   = pooled + (size_t)T_ * FLAT_;                  // 17.8 MB fp16
  float* feats     = (float*)(part + (size_t)T_ * FCH_ * FD_);     //  2.2 MB
  float* agg       = feats + (size_t)T_ * FD_;                     //  2.2 MB
  _Float16* wfrag  = (_Float16*)(agg + (size_t)T_ * FD_);          //  0.27 MB

  wfrag_prep_kernel<<<N_, 256, 0, stream>>>(conv_w, wfrag);
  conv_pool_kernel<<<T_, 256, 0, stream>>>(x, wfrag, conv_b, pooled);
  lin1_mfma_kernel<<<N_ * FCH_ * 2, 256, 0, stream>>>(pooled, lin1_w, part);
  feats_kernel<<<544, 256, 0, stream>>>(part, lin1_b, feats);
  gcn_agg_kernel<<<B_ * 2, 256, 0, stream>>>(feats, edge_idx, agg);
  gcn_head_kernel<<<B_, 512, 0, stream>>>(agg, gcn_w, gcn_b,
                                          mlp_w1, mlp_b1, mlp_w2, mlp_b2, outp);
}